// Round 1
// baseline (472.586 us; speedup 1.0000x reference)
//
#include <hip/hip_runtime.h>
#include <hip/hip_bf16.h>
#include <cstdint>

#define NWIN   1024
#define NTOK   98
#define BIAS_N 9604   // 98*98

typedef __attribute__((ext_vector_type(8))) short bf16x8;
typedef __attribute__((ext_vector_type(4))) float f32x4;

__device__ __forceinline__ float b2f(unsigned short u) {
  union { uint32_t i; float f; } v; v.i = ((uint32_t)u) << 16; return v.f;
}
__device__ __forceinline__ float b2f_lo(uint32_t u) {
  union { uint32_t i; float f; } v; v.i = u << 16; return v.f;
}
__device__ __forceinline__ float b2f_hi(uint32_t u) {
  union { uint32_t i; float f; } v; v.i = u & 0xffff0000u; return v.f;
}
__device__ __forceinline__ unsigned short f2b(float f) {  // RNE
  union { float f; uint32_t i; } v; v.f = f;
  uint32_t r = v.i + 0x7fffu + ((v.i >> 16) & 1u);
  return (unsigned short)(r >> 16);
}
__device__ __forceinline__ float ldf(const void* p, size_t i, int f32) {
  return f32 ? ((const float*)p)[i] : b2f(((const unsigned short*)p)[i]);
}
__device__ __forceinline__ void stf(void* p, size_t i, int f32, float v) {
  if (f32) ((float*)p)[i] = v;
  else     ((unsigned short*)p)[i] = f2b(v);
}
__device__ __forceinline__ float2 ldf2(const void* p, size_t i, int f32) {  // i even
  if (f32) { const float* q = (const float*)p + i; return make_float2(q[0], q[1]); }
  uint32_t u = *(const uint32_t*)((const unsigned short*)p + i);
  return make_float2(b2f_lo(u), b2f_hi(u));
}

// ws offsets (bytes)
#define QG_OFF   0
#define KG_OFF   25690112
#define VG_OFF   51380224
#define BIAS_OFF 77070336    // f32, 153664 B
#define WQ_OFF   77224000    // bf16 [384][128]
#define WP_OFF   77322304    // bf16 [128][128]
#define W1_OFF   77355072    // bf16 [512][128]
#define W2_OFF   77486144    // bf16 [128][512]
#define PAR_OFF  77617216    // f32 x 1664
#define FLAG_OFF 77623872
// param layout (float idx)
#define P_LN1G 0
#define P_LN1B 128
#define P_LN2G 256
#define P_LN2B 384
#define P_QKVB 512
#define P_PROJB 896
#define P_B1  1024
#define P_B2  1536

// ---------------- K0: detect float-tensor storage format ----------------
__global__ __launch_bounds__(256) void detect_kernel(const uint32_t* __restrict__ xw,
                                                     int* __restrict__ flag) {
  __shared__ int cnt;
  if (threadIdx.x == 0) cnt = 0;
  __syncthreads();
  uint32_t w = xw[threadIdx.x];
  int e = (w >> 23) & 0xFF;
  if (e >= 112 && e <= 134) atomicAdd(&cnt, 1);
  __syncthreads();
  if (threadIdx.x == 0) *flag = (cnt >= 128) ? 1 : 0;
}

// ---------------- K1: weight transpose->bf16 + param->f32 ----------------
__global__ __launch_bounds__(256) void prep_kernel(
    const void* __restrict__ qkvw, const void* __restrict__ projw,
    const void* __restrict__ w1, const void* __restrict__ w2,
    const void* __restrict__ ln1g, const void* __restrict__ ln1b,
    const void* __restrict__ ln2g, const void* __restrict__ ln2b,
    const void* __restrict__ qkvb, const void* __restrict__ projb,
    const void* __restrict__ b1, const void* __restrict__ b2,
    const int* __restrict__ flag,
    unsigned short* __restrict__ wq_t, unsigned short* __restrict__ wp_t,
    unsigned short* __restrict__ w1_t, unsigned short* __restrict__ w2_t,
    float* __restrict__ par) {
  const int f32 = *flag;
  int idx = blockIdx.x * 256 + threadIdx.x;
  if (idx < 49152) {
    int n = idx >> 7, k = idx & 127;
    wq_t[idx] = f2b(ldf(qkvw, (size_t)k * 384 + n, f32));
  } else if ((idx -= 49152) < 16384) {
    int n = idx >> 7, k = idx & 127;
    wp_t[idx] = f2b(ldf(projw, (size_t)k * 128 + n, f32));
  } else if ((idx -= 16384) < 65536) {
    int n = idx >> 7, k = idx & 127;
    w1_t[idx] = f2b(ldf(w1, (size_t)k * 512 + n, f32));
  } else if ((idx -= 65536) < 65536) {
    int n = idx >> 9, k = idx & 511;
    w2_t[idx] = f2b(ldf(w2, (size_t)k * 128 + n, f32));
  } else if ((idx -= 65536) < 1664) {
    float v;
    if      (idx < 128)  v = ldf(ln1g, idx, f32);
    else if (idx < 256)  v = ldf(ln1b, idx - 128, f32);
    else if (idx < 384)  v = ldf(ln2g, idx - 256, f32);
    else if (idx < 512)  v = ldf(ln2b, idx - 384, f32);
    else if (idx < 896)  v = ldf(qkvb, idx - 512, f32);
    else if (idx < 1024) v = ldf(projb, idx - 896, f32);
    else if (idx < 1536) v = ldf(b1, idx - 1024, f32);
    else                 v = ldf(b2, idx - 1536, f32);
    par[idx] = v;
  }
}

// ---------------- K2: bias[h][i*98+j] = table[rel_idx[i,j]][h] ----------------
__global__ __launch_bounds__(256) void bias_kernel(const int* __restrict__ rel_idx,
                                                   const void* __restrict__ tbl,
                                                   const int* __restrict__ flag,
                                                   float* __restrict__ bias) {
  const int f32 = *flag;
  int i = blockIdx.x * 256 + threadIdx.x;
  if (i >= 4 * BIAS_N) return;
  int h = i / BIAS_N, ij = i % BIAS_N;
  bias[i] = ldf(tbl, (size_t)rel_idx[ij] * 4 + h, f32);
}

// ---------------- K3: per-window LN1+gather + QKV MFMA ----------------
__global__ __launch_bounds__(256) void qkv_win_kernel(
    const void* __restrict__ x, const int* __restrict__ flag,
    const unsigned short* __restrict__ wq_t, const float* __restrict__ par,
    unsigned short* __restrict__ qg, unsigned short* __restrict__ kg,
    unsigned short* __restrict__ vg) {
  __shared__ unsigned short lnx[112 * 136];
  const int f32 = *flag;
  const int tid = threadIdx.x, wave = tid >> 6, lane = tid & 63;
  const int quad = lane >> 4, lcol = lane & 15;
  const int win = blockIdx.x;
  const int bb = win >> 8, r = win & 255;
  const int wd = r >> 6, r2 = r & 63, wh = r2 >> 3, ww = r2 & 7;

  for (int t = wave; t < NTOK; t += 4) {
    int td = t / 49, r3 = t % 49, th = r3 / 7, tw = r3 % 7;
    int sd = (wd * 2 + td + 1) & 7;
    int sh = (wh * 7 + th + 3) % 56;
    int sw = (ww * 7 + tw + 3) % 56;
    size_t src = ((((size_t)bb * 8 + sd) * 56 + sh) * 56 + sw) * 128;
    int c0 = lane * 2;
    float2 f = ldf2(x, src + c0, f32);
    float s = f.x + f.y, ss = f.x * f.x + f.y * f.y;
#pragma unroll
    for (int off = 32; off >= 1; off >>= 1) { s += __shfl_xor(s, off); ss += __shfl_xor(ss, off); }
    float mu = s * (1.0f / 128.0f);
    float var = ss * (1.0f / 128.0f) - mu * mu;
    float rs = rsqrtf(var + 1e-5f);
    float y0 = (f.x - mu) * rs * par[P_LN1G + c0] + par[P_LN1B + c0];
    float y1 = (f.y - mu) * rs * par[P_LN1G + c0 + 1] + par[P_LN1B + c0 + 1];
    *(uint32_t*)(lnx + t * 136 + c0) = (uint32_t)f2b(y0) | ((uint32_t)f2b(y1) << 16);
  }
  for (int i = tid; i < 14 * 68; i += 256) {
    int rr = i / 68, c = i % 68;
    *(uint32_t*)(lnx + (98 + rr) * 136 + c * 2) = 0u;
  }
  __syncthreads();

  for (int p = 0; p < 6; ++p) {
    const int n = p * 64 + wave * 16 + lcol;
    bf16x8 bfr[4];
#pragma unroll
    for (int ks = 0; ks < 4; ++ks)
      bfr[ks] = *(const bf16x8*)(wq_t + (size_t)n * 128 + ks * 32 + quad * 8);
    const int region = n >> 7, cc = n & 127, head = cc >> 5, d = cc & 31;
    unsigned short* dst = (region == 0 ? qg : (region == 1 ? kg : vg)) +
                          (((size_t)win * 4 + head) * NTOK) * 32 + d;
    const float bc = par[P_QKVB + n];
    const float scale = region == 0 ? 0.17677669529663687f : 1.0f;
    for (int mt = 0; mt < 7; ++mt) {
      f32x4 acc = (f32x4){0.f, 0.f, 0.f, 0.f};
#pragma unroll
      for (int ks = 0; ks < 4; ++ks) {
        bf16x8 a = *(const bf16x8*)(lnx + (mt * 16 + lcol) * 136 + ks * 32 + quad * 8);
        acc = __builtin_amdgcn_mfma_f32_16x16x32_bf16(a, bfr[ks], acc, 0, 0, 0);
      }
#pragma unroll
      for (int rr = 0; rr < 4; ++rr) {
        int m = mt * 16 + quad * 4 + rr;
        if (m < NTOK) dst[m * 32] = f2b((acc[rr] + bc) * scale);
      }
    }
  }
}

// ---------------- K4: fused MFMA attention + proj + residual, 1 block/window ----------------
__global__ __launch_bounds__(256) void attn_fused_kernel(
    const unsigned short* __restrict__ qg, const unsigned short* __restrict__ kg,
    const unsigned short* __restrict__ vg, const float* __restrict__ bias,
    const unsigned short* __restrict__ wp_t, const float* __restrict__ par,
    const void* __restrict__ x, const int* __restrict__ flag,
    void* __restrict__ out) {
  __shared__ unsigned short smem[26112];   // 52224 B: vt[4][32*136] | pl[4][16*136]; olds overlays
  const int f32 = *flag;
  const int tid = threadIdx.x, wave = tid >> 6, lane = tid & 63;
  const int quad = lane >> 4, lcol = lane & 15;
  const int win = blockIdx.x, h = wave;
  const size_t hb = (((size_t)win * 4 + h) * NTOK) * 32;

  unsigned short* vth = smem + h * (32 * 136);
  unsigned short* plh = smem + 17408 + h * (16 * 136);

  // ---- stage V^T (vt[d][j] = V[j][d]), zero pads; zero pl cols 112..127 ----
  {
    const uint32_t* vsrc = (const uint32_t*)(vg + hb);
    for (int idx = lane; idx < NTOK * 16; idx += 64) {
      int j = idx >> 4, dp = idx & 15;
      uint32_t u = vsrc[idx];
      vth[(2 * dp) * 136 + j]     = (unsigned short)(u & 0xffffu);
      vth[(2 * dp + 1) * 136 + j] = (unsigned short)(u >> 16);
    }
    for (int idx = lane; idx < 32 * 30; idx += 64) {
      int d = idx / 30, c = 98 + idx % 30;
      vth[d * 136 + c] = 0;
    }
    for (int idx = lane; idx < 16 * 16; idx += 64) {
      int rr = idx >> 4, c = 112 + (idx & 15);
      plh[rr * 136 + c] = 0;
    }
  }
  __syncthreads();

  // ---- Q/K fragments direct from global (rows clamped at 97; pad rows discarded) ----
  bf16x8 aq[7], bk[7];
#pragma unroll
  for (int t = 0; t < 7; ++t) {
    int row = min(t * 16 + lcol, NTOK - 1);
    aq[t] = *(const bf16x8*)(qg + hb + (size_t)row * 32 + quad * 8);
    bk[t] = *(const bf16x8*)(kg + hb + (size_t)row * 32 + quad * 8);
  }

  const float* bh = bias + h * BIAS_N;
  f32x4 o[7][2];
  for (int mt = 0; mt < 7; ++mt) {
    // scores S[i][j], i = mt*16+quad*4+r, j = nt*16+lcol
    f32x4 s[7];
#pragma unroll
    for (int nt = 0; nt < 7; ++nt)
      s[nt] = __builtin_amdgcn_mfma_f32_16x16x32_bf16(aq[mt], bk[nt],
                                                      (f32x4){0.f, 0.f, 0.f, 0.f}, 0, 0, 0);
    const int ib = mt * 16 + quad * 4;
#pragma unroll
    for (int nt = 0; nt < 7; ++nt) {
      int j = nt * 16 + lcol;
      bool jv = j < NTOK;
#pragma unroll
      for (int r = 0; r < 4; ++r) {
        int ic = min(ib + r, NTOK - 1);
        s[nt][r] = jv ? (s[nt][r] + bh[ic * NTOK + j]) : -3.0e38f;
      }
    }
    // row softmax: local over nt, then shfl_xor across the 16-lane column group
    float mx[4], sum[4], inv[4];
#pragma unroll
    for (int r = 0; r < 4; ++r) {
      float m = s[0][r];
#pragma unroll
      for (int nt = 1; nt < 7; ++nt) m = fmaxf(m, s[nt][r]);
      mx[r] = m;
    }
#pragma unroll
    for (int off = 1; off < 16; off <<= 1)
#pragma unroll
      for (int r = 0; r < 4; ++r) mx[r] = fmaxf(mx[r], __shfl_xor(mx[r], off));
#pragma unroll
    for (int r = 0; r < 4; ++r) sum[r] = 0.f;
#pragma unroll
    for (int nt = 0; nt < 7; ++nt)
#pragma unroll
      for (int r = 0; r < 4; ++r) {
        float e = __expf(s[nt][r] - mx[r]);
        s[nt][r] = e; sum[r] += e;
      }
#pragma unroll
    for (int off = 1; off < 16; off <<= 1)
#pragma unroll
      for (int r = 0; r < 4; ++r) sum[r] += __shfl_xor(sum[r], off);
#pragma unroll
    for (int r = 0; r < 4; ++r) inv[r] = 1.0f / sum[r];
    // write P (bf16) to own LDS tile in A-layout source form [i][j]
#pragma unroll
    for (int nt = 0; nt < 7; ++nt)
#pragma unroll
      for (int r = 0; r < 4; ++r)
        plh[(quad * 4 + r) * 136 + nt * 16 + lcol] = f2b(s[nt][r] * inv[r]);
    __syncthreads();
    // PV: A = P tile (K=128 padded with zeros), B = V^T
#pragma unroll
    for (int n2 = 0; n2 < 2; ++n2) {
      f32x4 acc = (f32x4){0.f, 0.f, 0.f, 0.f};
#pragma unroll
      for (int kp = 0; kp < 4; ++kp) {
        bf16x8 a = *(const bf16x8*)(plh + lcol * 136 + kp * 32 + quad * 8);
        bf16x8 b = *(const bf16x8*)(vth + (n2 * 16 + lcol) * 136 + kp * 32 + quad * 8);
        acc = __builtin_amdgcn_mfma_f32_16x16x32_bf16(a, b, acc, 0, 0, 0);
      }
      o[mt][n2] = acc;
    }
  }
  __syncthreads();   // all PV reads done before olds overlays vt/pl

  // ---- attn-out -> LDS [112][136], full 128 channels ----
  unsigned short* olds = smem;
#pragma unroll
  for (int mt = 0; mt < 7; ++mt)
#pragma unroll
    for (int n2 = 0; n2 < 2; ++n2)
#pragma unroll
      for (int r = 0; r < 4; ++r)
        olds[(mt * 16 + quad * 4 + r) * 136 + h * 32 + n2 * 16 + lcol] = f2b(o[mt][n2][r]);
  __syncthreads();

  // ---- proj + bias + residual scatter (reverse roll) ----
  const int bb = win >> 8, rW = win & 255;
  const int wd = rW >> 6, r2 = rW & 63, wh = r2 >> 3, ww = r2 & 7;
  for (int t2 = 0; t2 < 2; ++t2) {
    const int n = (h * 2 + t2) * 16 + lcol;
    bf16x8 bw[4];
#pragma unroll
    for (int kp = 0; kp < 4; ++kp)
      bw[kp] = *(const bf16x8*)(wp_t + (size_t)n * 128 + kp * 32 + quad * 8);
    const float bc = par[P_PROJB + n];
    for (int mt = 0; mt < 7; ++mt) {
      f32x4 acc = (f32x4){0.f, 0.f, 0.f, 0.f};
#pragma unroll
      for (int kp = 0; kp < 4; ++kp) {
        bf16x8 a = *(const bf16x8*)(olds + (mt * 16 + lcol) * 136 + kp * 32 + quad * 8);
        acc = __builtin_amdgcn_mfma_f32_16x16x32_bf16(a, bw[kp], acc, 0, 0, 0);
      }
#pragma unroll
      for (int r = 0; r < 4; ++r) {
        int m = mt * 16 + quad * 4 + r;
        if (m < NTOK) {
          int td = m / 49, r3 = m % 49, th = r3 / 7, tw = r3 % 7;
          int sd = (wd * 2 + td + 1) & 7;
          int sh = (wh * 7 + th + 3) % 56;
          int sw = (ww * 7 + tw + 3) % 56;
          size_t oidx = ((((size_t)bb * 8 + sd) * 56 + sh) * 56 + sw) * 128 + n;
          stf(out, oidx, f32, acc[r] + bc + ldf(x, oidx, f32));
        }
      }
    }
  }
}

// ---------------- K5: LN2 + MLP1(gelu) + MLP2 + residual ----------------
__global__ __launch_bounds__(256) void mlp_kernel(
    const unsigned short* __restrict__ w1_t, const unsigned short* __restrict__ w2_t,
    const float* __restrict__ par, const int* __restrict__ flag,
    void* __restrict__ out) {
  __shared__ unsigned short lnt[32 * 136];
  __shared__ unsigned short hbuf[32 * 520];
  const int f32 = *flag;
  const int tid = threadIdx.x, wave = tid >> 6, lane = tid & 63;
  const int quad = lane >> 4, lcol = lane & 15;
  const int m0 = blockIdx.x * 32;

  for (int t = wave; t < 32; t += 4) {
    int c0 = lane * 2;
    float2 f = ldf2(out, (size_t)(m0 + t) * 128 + c0, f32);
    float s = f.x + f.y, ss = f.x * f.x + f.y * f.y;
#pragma unroll
    for (int off = 32; off >= 1; off >>= 1) { s += __shfl_xor(s, off); ss += __shfl_xor(ss, off); }
    float mu = s * (1.0f / 128.0f);
    float var = ss * (1.0f / 128.0f) - mu * mu;
    float rs = rsqrtf(var + 1e-5f);
    float y0 = (f.x - mu) * rs * par[P_LN2G + c0] + par[P_LN2B + c0];
    float y1 = (f.y - mu) * rs * par[P_LN2G + c0 + 1] + par[P_LN2B + c0 + 1];
    *(uint32_t*)(lnt + t * 136 + c0) = (uint32_t)f2b(y0) | ((uint32_t)f2b(y1) << 16);
  }
  __syncthreads();

  for (int p = 0; p < 8; ++p) {
    const int n = p * 64 + wave * 16 + lcol;
    bf16x8 bfr[4];
#pragma unroll
    for (int ks = 0; ks < 4; ++ks)
      bfr[ks] = *(const bf16x8*)(w1_t + (size_t)n * 128 + ks * 32 + quad * 8);
    const float bc = par[P_B1 + n];
#pragma unroll
    for (int mt = 0; mt < 2; ++mt) {
      f32x4 acc = (f32x4){0.f, 0.f, 0.f, 0.f};
#pragma unroll
      for (int ks = 0; ks < 4; ++ks) {
        bf16x8 a = *(const bf16x8*)(lnt + (mt * 16 + lcol) * 136 + ks * 32 + quad * 8);
        acc = __builtin_amdgcn_mfma_f32_16x16x32_bf16(a, bfr[ks], acc, 0, 0, 0);
      }
#pragma unroll
      for (int rr = 0; rr < 4; ++rr) {
        int m = mt * 16 + quad * 4 + rr;
        float v = acc[rr] + bc;
        v = 0.5f * v * (1.0f + erff(v * 0.70710678118654752f));
        hbuf[m * 520 + n] = f2b(v);
      }
    }
  }
  __syncthreads();

  f32x4 acc2[2][2];
#pragma unroll
  for (int a = 0; a < 2; ++a)
#pragma unroll
    for (int b = 0; b < 2; ++b) acc2[a][b] = (f32x4){0.f, 0.f, 0.f, 0.f};
#pragma unroll
  for (int np = 0; np < 2; ++np) {
    const int n = np * 64 + wave * 16 + lcol;
    for (int kp = 0; kp < 4; ++kp) {
      bf16x8 bfr[4];
#pragma unroll
      for (int ks = 0; ks < 4; ++ks)
        bfr[ks] = *(const bf16x8*)(w2_t + (size_t)n * 512 + kp * 128 + ks * 32 + quad * 8);
#pragma unroll
      for (int mt = 0; mt < 2; ++mt) {
#pragma unroll
        for (int ks = 0; ks < 4; ++ks) {
          bf16x8 a = *(const bf16x8*)(hbuf + (mt * 16 + lcol) * 520 + kp * 128 +
                                      ks * 32 + quad * 8);
          acc2[np][mt] = __builtin_amdgcn_mfma_f32_16x16x32_bf16(a, bfr[ks], acc2[np][mt], 0, 0, 0);
        }
      }
    }
  }
#pragma unroll
  for (int np = 0; np < 2; ++np) {
    const int n = np * 64 + wave * 16 + lcol;
    const float bc = par[P_B2 + n];
#pragma unroll
    for (int mt = 0; mt < 2; ++mt) {
#pragma unroll
      for (int rr = 0; rr < 4; ++rr) {
        size_t oi = (size_t)(m0 + mt * 16 + quad * 4 + rr) * 128 + n;
        stf(out, oi, f32, acc2[np][mt][rr] + bc + ldf(out, oi, f32));
      }
    }
  }
}

// ---------------- host launch ----------------
extern "C" void kernel_launch(void* const* d_in, const int* in_sizes, int n_in,
                              void* d_out, int out_size, void* d_ws, size_t ws_size,
                              hipStream_t stream) {
  const void* x      = d_in[0];
  const int*  rel    = (const int*)d_in[1];
  const void* rpb    = d_in[2];
  const void* qkv_w  = d_in[3];
  const void* qkv_b  = d_in[4];
  const void* proj_w = d_in[5];
  const void* proj_b = d_in[6];
  const void* ln1_g  = d_in[7];
  const void* ln1_b  = d_in[8];
  const void* ln2_g  = d_in[9];
  const void* ln2_b  = d_in[10];
  const void* w1     = d_in[11];
  const void* b1     = d_in[12];
  const void* w2     = d_in[13];
  const void* b2     = d_in[14];

  char* ws = (char*)d_ws;
  unsigned short* qg   = (unsigned short*)(ws + QG_OFF);
  unsigned short* kg   = (unsigned short*)(ws + KG_OFF);
  unsigned short* vg   = (unsigned short*)(ws + VG_OFF);
  float*          bias = (float*)(ws + BIAS_OFF);
  unsigned short* wq_t = (unsigned short*)(ws + WQ_OFF);
  unsigned short* wp_t = (unsigned short*)(ws + WP_OFF);
  unsigned short* w1_t = (unsigned short*)(ws + W1_OFF);
  unsigned short* w2_t = (unsigned short*)(ws + W2_OFF);
  float*          par  = (float*)(ws + PAR_OFF);
  int*            flag = (int*)(ws + FLAG_OFF);

  detect_kernel<<<1, 256, 0, stream>>>((const uint32_t*)x, flag);
  prep_kernel<<<775, 256, 0, stream>>>(qkv_w, proj_w, w1, w2, ln1_g, ln1_b, ln2_g,
                                       ln2_b, qkv_b, proj_b, b1, b2, flag,
                                       wq_t, wp_t, w1_t, w2_t, par);
  bias_kernel<<<(4 * BIAS_N + 255) / 256, 256, 0, stream>>>(rel, rpb, flag, bias);
  qkv_win_kernel<<<NWIN, 256, 0, stream>>>(x, flag, wq_t, par, qg, kg, vg);
  attn_fused_kernel<<<NWIN, 256, 0, stream>>>(qg, kg, vg, bias, wp_t, par, x, flag, d_out);
  mlp_kernel<<<100352 / 32, 256, 0, stream>>>(w1_t, w2_t, par, flag, d_out);
}

// Round 2
// 440.173 us; speedup vs baseline: 1.0736x; 1.0736x over previous
//
#include <hip/hip_runtime.h>
#include <hip/hip_bf16.h>
#include <cstdint>

#define NWIN   1024
#define NTOK   98
#define BIAS_N 9604   // 98*98

typedef __attribute__((ext_vector_type(8))) short bf16x8;
typedef __attribute__((ext_vector_type(4))) float f32x4;

__device__ __forceinline__ float b2f(unsigned short u) {
  union { uint32_t i; float f; } v; v.i = ((uint32_t)u) << 16; return v.f;
}
__device__ __forceinline__ float b2f_lo(uint32_t u) {
  union { uint32_t i; float f; } v; v.i = u << 16; return v.f;
}
__device__ __forceinline__ float b2f_hi(uint32_t u) {
  union { uint32_t i; float f; } v; v.i = u & 0xffff0000u; return v.f;
}
__device__ __forceinline__ unsigned short f2b(float f) {  // RNE
  union { float f; uint32_t i; } v; v.f = f;
  uint32_t r = v.i + 0x7fffu + ((v.i >> 16) & 1u);
  return (unsigned short)(r >> 16);
}
__device__ __forceinline__ float ldf(const void* p, size_t i, int f32) {
  return f32 ? ((const float*)p)[i] : b2f(((const unsigned short*)p)[i]);
}
__device__ __forceinline__ void stf(void* p, size_t i, int f32, float v) {
  if (f32) ((float*)p)[i] = v;
  else     ((unsigned short*)p)[i] = f2b(v);
}
__device__ __forceinline__ float2 ldf2(const void* p, size_t i, int f32) {  // i even
  if (f32) { const float* q = (const float*)p + i; return make_float2(q[0], q[1]); }
  uint32_t u = *(const uint32_t*)((const unsigned short*)p + i);
  return make_float2(b2f_lo(u), b2f_hi(u));
}

// ws offsets (bytes)
#define QG_OFF   0
#define KG_OFF   25690112
#define VG_OFF   51380224
#define BIAS_OFF 77070336    // f32, 153664 B
#define WQ_OFF   77224000    // bf16 [384][128]
#define WP_OFF   77322304    // bf16 [128][128]
#define W1_OFF   77355072    // bf16 [512][128]
#define W2_OFF   77486144    // bf16 [128][512]
#define PAR_OFF  77617216    // f32 x 1664
#define FLAG_OFF 77623872
// param layout (float idx)
#define P_LN1G 0
#define P_LN1B 128
#define P_LN2G 256
#define P_LN2B 384
#define P_QKVB 512
#define P_PROJB 896
#define P_B1  1024
#define P_B2  1536

// ---------------- K0: detect float-tensor storage format ----------------
__global__ __launch_bounds__(256) void detect_kernel(const uint32_t* __restrict__ xw,
                                                     int* __restrict__ flag) {
  __shared__ int cnt;
  if (threadIdx.x == 0) cnt = 0;
  __syncthreads();
  uint32_t w = xw[threadIdx.x];
  int e = (w >> 23) & 0xFF;
  if (e >= 112 && e <= 134) atomicAdd(&cnt, 1);
  __syncthreads();
  if (threadIdx.x == 0) *flag = (cnt >= 128) ? 1 : 0;
}

// ---------------- K1: weight transpose->bf16 + param->f32 ----------------
__global__ __launch_bounds__(256) void prep_kernel(
    const void* __restrict__ qkvw, const void* __restrict__ projw,
    const void* __restrict__ w1, const void* __restrict__ w2,
    const void* __restrict__ ln1g, const void* __restrict__ ln1b,
    const void* __restrict__ ln2g, const void* __restrict__ ln2b,
    const void* __restrict__ qkvb, const void* __restrict__ projb,
    const void* __restrict__ b1, const void* __restrict__ b2,
    const int* __restrict__ flag,
    unsigned short* __restrict__ wq_t, unsigned short* __restrict__ wp_t,
    unsigned short* __restrict__ w1_t, unsigned short* __restrict__ w2_t,
    float* __restrict__ par) {
  const int f32 = *flag;
  int idx = blockIdx.x * 256 + threadIdx.x;
  if (idx < 49152) {
    int n = idx >> 7, k = idx & 127;
    wq_t[idx] = f2b(ldf(qkvw, (size_t)k * 384 + n, f32));
  } else if ((idx -= 49152) < 16384) {
    int n = idx >> 7, k = idx & 127;
    wp_t[idx] = f2b(ldf(projw, (size_t)k * 128 + n, f32));
  } else if ((idx -= 16384) < 65536) {
    int n = idx >> 7, k = idx & 127;
    w1_t[idx] = f2b(ldf(w1, (size_t)k * 512 + n, f32));
  } else if ((idx -= 65536) < 65536) {
    int n = idx >> 9, k = idx & 511;
    w2_t[idx] = f2b(ldf(w2, (size_t)k * 128 + n, f32));
  } else if ((idx -= 65536) < 1664) {
    float v;
    if      (idx < 128)  v = ldf(ln1g, idx, f32);
    else if (idx < 256)  v = ldf(ln1b, idx - 128, f32);
    else if (idx < 384)  v = ldf(ln2g, idx - 256, f32);
    else if (idx < 512)  v = ldf(ln2b, idx - 384, f32);
    else if (idx < 896)  v = ldf(qkvb, idx - 512, f32);
    else if (idx < 1024) v = ldf(projb, idx - 896, f32);
    else if (idx < 1536) v = ldf(b1, idx - 1024, f32);
    else                 v = ldf(b2, idx - 1536, f32);
    par[idx] = v;
  }
}

// ---------------- K2: bias[h][i*98+j] = table[rel_idx[i,j]][h] ----------------
__global__ __launch_bounds__(256) void bias_kernel(const int* __restrict__ rel_idx,
                                                   const void* __restrict__ tbl,
                                                   const int* __restrict__ flag,
                                                   float* __restrict__ bias) {
  const int f32 = *flag;
  int i = blockIdx.x * 256 + threadIdx.x;
  if (i >= 4 * BIAS_N) return;
  int h = i / BIAS_N, ij = i % BIAS_N;
  bias[i] = ldf(tbl, (size_t)rel_idx[ij] * 4 + h, f32);
}

// ---------------- K3: per-window LN1+gather + QKV MFMA ----------------
__global__ __launch_bounds__(256) void qkv_win_kernel(
    const void* __restrict__ x, const int* __restrict__ flag,
    const unsigned short* __restrict__ wq_t, const float* __restrict__ par,
    unsigned short* __restrict__ qg, unsigned short* __restrict__ kg,
    unsigned short* __restrict__ vg) {
  __shared__ unsigned short lnx[112 * 136];
  const int f32 = *flag;
  const int tid = threadIdx.x, wave = tid >> 6, lane = tid & 63;
  const int quad = lane >> 4, lcol = lane & 15;
  const int win = blockIdx.x;
  const int bb = win >> 8, r = win & 255;
  const int wd = r >> 6, r2 = r & 63, wh = r2 >> 3, ww = r2 & 7;

  for (int t = wave; t < NTOK; t += 4) {
    int td = t / 49, r3 = t % 49, th = r3 / 7, tw = r3 % 7;
    int sd = (wd * 2 + td + 1) & 7;
    int sh = (wh * 7 + th + 3) % 56;
    int sw = (ww * 7 + tw + 3) % 56;
    size_t src = ((((size_t)bb * 8 + sd) * 56 + sh) * 56 + sw) * 128;
    int c0 = lane * 2;
    float2 f = ldf2(x, src + c0, f32);
    float s = f.x + f.y, ss = f.x * f.x + f.y * f.y;
#pragma unroll
    for (int off = 32; off >= 1; off >>= 1) { s += __shfl_xor(s, off); ss += __shfl_xor(ss, off); }
    float mu = s * (1.0f / 128.0f);
    float var = ss * (1.0f / 128.0f) - mu * mu;
    float rs = rsqrtf(var + 1e-5f);
    float y0 = (f.x - mu) * rs * par[P_LN1G + c0] + par[P_LN1B + c0];
    float y1 = (f.y - mu) * rs * par[P_LN1G + c0 + 1] + par[P_LN1B + c0 + 1];
    *(uint32_t*)(lnx + t * 136 + c0) = (uint32_t)f2b(y0) | ((uint32_t)f2b(y1) << 16);
  }
  for (int i = tid; i < 14 * 68; i += 256) {
    int rr = i / 68, c = i % 68;
    *(uint32_t*)(lnx + (98 + rr) * 136 + c * 2) = 0u;
  }
  __syncthreads();

  for (int p = 0; p < 6; ++p) {
    const int n = p * 64 + wave * 16 + lcol;
    bf16x8 bfr[4];
#pragma unroll
    for (int ks = 0; ks < 4; ++ks)
      bfr[ks] = *(const bf16x8*)(wq_t + (size_t)n * 128 + ks * 32 + quad * 8);
    const int region = n >> 7, cc = n & 127, head = cc >> 5, d = cc & 31;
    unsigned short* dst = (region == 0 ? qg : (region == 1 ? kg : vg)) +
                          (((size_t)win * 4 + head) * NTOK) * 32 + d;
    const float bc = par[P_QKVB + n];
    const float scale = region == 0 ? 0.17677669529663687f : 1.0f;
    for (int mt = 0; mt < 7; ++mt) {
      f32x4 acc = (f32x4){0.f, 0.f, 0.f, 0.f};
#pragma unroll
      for (int ks = 0; ks < 4; ++ks) {
        bf16x8 a = *(const bf16x8*)(lnx + (mt * 16 + lcol) * 136 + ks * 32 + quad * 8);
        acc = __builtin_amdgcn_mfma_f32_16x16x32_bf16(a, bfr[ks], acc, 0, 0, 0);
      }
#pragma unroll
      for (int rr = 0; rr < 4; ++rr) {
        int m = mt * 16 + quad * 4 + rr;
        if (m < NTOK) dst[m * 32] = f2b((acc[rr] + bc) * scale);
      }
    }
  }
}

// ---------------- K4: fused MFMA attention + proj + residual, 1 block/window ----------------
// Changes vs r1: (a) vth/plh are wave-private -> staging barrier + 7 per-mt barriers
// removed (same-wave ds ordering via lgkmcnt); (b) epilogue restaged: proj+bias -> f32
// LDS pout[98][132] -> cooperative 512B-contiguous per-token residual add + store
// (removes 64B-granule write/read amplification: WRITE_SIZE 117MB -> ~54MB predicted).
__global__ __launch_bounds__(256) void attn_fused_kernel(
    const unsigned short* __restrict__ qg, const unsigned short* __restrict__ kg,
    const unsigned short* __restrict__ vg, const float* __restrict__ bias,
    const unsigned short* __restrict__ wp_t, const float* __restrict__ par,
    const void* __restrict__ x, const int* __restrict__ flag,
    void* __restrict__ out) {
  __shared__ __align__(16) unsigned short smem[26112];  // 52224 B
  const int f32 = *flag;
  const int tid = threadIdx.x, wave = tid >> 6, lane = tid & 63;
  const int quad = lane >> 4, lcol = lane & 15;
  const int win = blockIdx.x, h = wave;
  const size_t hb = (((size_t)win * 4 + h) * NTOK) * 32;

  unsigned short* vth = smem + h * (32 * 136);
  unsigned short* plh = smem + 17408 + h * (16 * 136);

  // ---- stage V^T (vt[d][j] = V[j][d]), zero pads; all wave-private, no barrier ----
  {
    const uint32_t* vsrc = (const uint32_t*)(vg + hb);
    for (int idx = lane; idx < NTOK * 16; idx += 64) {
      int j = idx >> 4, dp = idx & 15;
      uint32_t u = vsrc[idx];
      vth[(2 * dp) * 136 + j]     = (unsigned short)(u & 0xffffu);
      vth[(2 * dp + 1) * 136 + j] = (unsigned short)(u >> 16);
    }
    for (int idx = lane; idx < 32 * 30; idx += 64) {
      int d = idx / 30, c = 98 + idx % 30;
      vth[d * 136 + c] = 0;
    }
    for (int idx = lane; idx < 16 * 16; idx += 64) {
      int rr = idx >> 4, c = 112 + (idx & 15);
      plh[rr * 136 + c] = 0;
    }
  }

  // ---- Q/K fragments direct from global (rows clamped at 97; pad rows discarded) ----
  bf16x8 aq[7], bk[7];
#pragma unroll
  for (int t = 0; t < 7; ++t) {
    int row = min(t * 16 + lcol, NTOK - 1);
    aq[t] = *(const bf16x8*)(qg + hb + (size_t)row * 32 + quad * 8);
    bk[t] = *(const bf16x8*)(kg + hb + (size_t)row * 32 + quad * 8);
  }

  const float* bh = bias + h * BIAS_N;
  f32x4 o[7][2];
  for (int mt = 0; mt < 7; ++mt) {
    // scores S[i][j], i = mt*16+quad*4+r, j = nt*16+lcol
    f32x4 s[7];
#pragma unroll
    for (int nt = 0; nt < 7; ++nt)
      s[nt] = __builtin_amdgcn_mfma_f32_16x16x32_bf16(aq[mt], bk[nt],
                                                      (f32x4){0.f, 0.f, 0.f, 0.f}, 0, 0, 0);
    const int ib = mt * 16 + quad * 4;
#pragma unroll
    for (int nt = 0; nt < 7; ++nt) {
      int j = nt * 16 + lcol;
      bool jv = j < NTOK;
#pragma unroll
      for (int r = 0; r < 4; ++r) {
        int ic = min(ib + r, NTOK - 1);
        s[nt][r] = jv ? (s[nt][r] + bh[ic * NTOK + j]) : -3.0e38f;
      }
    }
    // row softmax: local over nt, then shfl_xor across the 16-lane column group
    float mx[4], sum[4], inv[4];
#pragma unroll
    for (int r = 0; r < 4; ++r) {
      float m = s[0][r];
#pragma unroll
      for (int nt = 1; nt < 7; ++nt) m = fmaxf(m, s[nt][r]);
      mx[r] = m;
    }
#pragma unroll
    for (int off = 1; off < 16; off <<= 1)
#pragma unroll
      for (int r = 0; r < 4; ++r) mx[r] = fmaxf(mx[r], __shfl_xor(mx[r], off));
#pragma unroll
    for (int r = 0; r < 4; ++r) sum[r] = 0.f;
#pragma unroll
    for (int nt = 0; nt < 7; ++nt)
#pragma unroll
      for (int r = 0; r < 4; ++r) {
        float e = __expf(s[nt][r] - mx[r]);
        s[nt][r] = e; sum[r] += e;
      }
#pragma unroll
    for (int off = 1; off < 16; off <<= 1)
#pragma unroll
      for (int r = 0; r < 4; ++r) sum[r] += __shfl_xor(sum[r], off);
#pragma unroll
    for (int r = 0; r < 4; ++r) inv[r] = 1.0f / sum[r];
    // write P (bf16) to own LDS tile in A-layout source form [i][j] (wave-private)
#pragma unroll
    for (int nt = 0; nt < 7; ++nt)
#pragma unroll
      for (int r = 0; r < 4; ++r)
        plh[(quad * 4 + r) * 136 + nt * 16 + lcol] = f2b(s[nt][r] * inv[r]);
    // PV: A = P tile (K=128 padded with zeros), B = V^T  (no block barrier: same-wave dep)
#pragma unroll
    for (int n2 = 0; n2 < 2; ++n2) {
      f32x4 acc = (f32x4){0.f, 0.f, 0.f, 0.f};
#pragma unroll
      for (int kp = 0; kp < 4; ++kp) {
        bf16x8 a = *(const bf16x8*)(plh + lcol * 136 + kp * 32 + quad * 8);
        bf16x8 b = *(const bf16x8*)(vth + (n2 * 16 + lcol) * 136 + kp * 32 + quad * 8);
        acc = __builtin_amdgcn_mfma_f32_16x16x32_bf16(a, b, acc, 0, 0, 0);
      }
      o[mt][n2] = acc;
    }
  }
  __syncthreads();   // all waves' PV reads done before olds overlays vt/pl

  // ---- attn-out -> LDS [112][136], full 128 channels ----
  unsigned short* olds = smem;
#pragma unroll
  for (int mt = 0; mt < 7; ++mt)
#pragma unroll
    for (int n2 = 0; n2 < 2; ++n2)
#pragma unroll
      for (int r = 0; r < 4; ++r)
        olds[(mt * 16 + quad * 4 + r) * 136 + h * 32 + n2 * 16 + lcol] = f2b(o[mt][n2][r]);
  __syncthreads();

  // ---- proj into registers ----
  f32x4 pr[2][7];
  for (int t2 = 0; t2 < 2; ++t2) {
    const int n = (h * 2 + t2) * 16 + lcol;
    bf16x8 bw[4];
#pragma unroll
    for (int kp = 0; kp < 4; ++kp)
      bw[kp] = *(const bf16x8*)(wp_t + (size_t)n * 128 + kp * 32 + quad * 8);
    for (int mt = 0; mt < 7; ++mt) {
      f32x4 acc = (f32x4){0.f, 0.f, 0.f, 0.f};
#pragma unroll
      for (int kp = 0; kp < 4; ++kp) {
        bf16x8 a = *(const bf16x8*)(olds + (mt * 16 + lcol) * 136 + kp * 32 + quad * 8);
        acc = __builtin_amdgcn_mfma_f32_16x16x32_bf16(a, bw[kp], acc, 0, 0, 0);
      }
      pr[t2][mt] = acc;
    }
  }
  __syncthreads();   // all olds reads done before pout overlays smem

  // ---- stage proj+bias (f32) -> pout[98][132] ----
  float* pout = (float*)smem;
  for (int t2 = 0; t2 < 2; ++t2) {
    const int n = (h * 2 + t2) * 16 + lcol;
    const float bc = par[P_PROJB + n];
#pragma unroll
    for (int mt = 0; mt < 7; ++mt)
#pragma unroll
      for (int r = 0; r < 4; ++r) {
        int m = mt * 16 + quad * 4 + r;
        if (m < NTOK) pout[m * 132 + n] = pr[t2][mt][r] + bc;
      }
  }
  __syncthreads();

  // ---- coalesced residual + store: one 512B token row per 32-thread group ----
  const int bb = win >> 8, rW = win & 255;
  const int wd = rW >> 6, r2 = rW & 63, wh = r2 >> 3, ww = r2 & 7;
  const int c = (tid & 31) * 4;
  for (int m = tid >> 5; m < NTOK; m += 8) {
    int td = m / 49, r3 = m % 49, th = r3 / 7, tw = r3 % 7;
    int sd = (wd * 2 + td + 1) & 7;
    int sh = (wh * 7 + th + 3) % 56;
    int sw = (ww * 7 + tw + 3) % 56;
    size_t base = ((((size_t)bb * 8 + sd) * 56 + sh) * 56 + sw) * 128 + c;
    float4 p = *(const float4*)(pout + m * 132 + c);
    if (f32) {
      const float4 xr = *(const float4*)((const float*)x + base);
      float4 ov = make_float4(p.x + xr.x, p.y + xr.y, p.z + xr.z, p.w + xr.w);
      *(float4*)((float*)out + base) = ov;
    } else {
      const ushort4 xr = *(const ushort4*)((const unsigned short*)x + base);
      ushort4 ov;
      ov.x = f2b(p.x + b2f(xr.x)); ov.y = f2b(p.y + b2f(xr.y));
      ov.z = f2b(p.z + b2f(xr.z)); ov.w = f2b(p.w + b2f(xr.w));
      *(ushort4*)((unsigned short*)out + base) = ov;
    }
  }
}

// ---------------- K5: LN2 + MLP1(gelu) + MLP2 + residual ----------------
// Changes vs r1: epilogue restaged through f32 LDS pout[32][132] (overlays hbuf) ->
// fully coalesced float4 read-modify-write of the contiguous 16KB output block.
__global__ __launch_bounds__(256) void mlp_kernel(
    const unsigned short* __restrict__ w1_t, const unsigned short* __restrict__ w2_t,
    const float* __restrict__ par, const int* __restrict__ flag,
    void* __restrict__ out) {
  __shared__ __align__(16) unsigned short lnt[32 * 136];
  __shared__ __align__(16) unsigned short hbuf[32 * 520];
  const int f32 = *flag;
  const int tid = threadIdx.x, wave = tid >> 6, lane = tid & 63;
  const int quad = lane >> 4, lcol = lane & 15;
  const int m0 = blockIdx.x * 32;

  for (int t = wave; t < 32; t += 4) {
    int c0 = lane * 2;
    float2 f = ldf2(out, (size_t)(m0 + t) * 128 + c0, f32);
    float s = f.x + f.y, ss = f.x * f.x + f.y * f.y;
#pragma unroll
    for (int off = 32; off >= 1; off >>= 1) { s += __shfl_xor(s, off); ss += __shfl_xor(ss, off); }
    float mu = s * (1.0f / 128.0f);
    float var = ss * (1.0f / 128.0f) - mu * mu;
    float rs = rsqrtf(var + 1e-5f);
    float y0 = (f.x - mu) * rs * par[P_LN2G + c0] + par[P_LN2B + c0];
    float y1 = (f.y - mu) * rs * par[P_LN2G + c0 + 1] + par[P_LN2B + c0 + 1];
    *(uint32_t*)(lnt + t * 136 + c0) = (uint32_t)f2b(y0) | ((uint32_t)f2b(y1) << 16);
  }
  __syncthreads();

  for (int p = 0; p < 8; ++p) {
    const int n = p * 64 + wave * 16 + lcol;
    bf16x8 bfr[4];
#pragma unroll
    for (int ks = 0; ks < 4; ++ks)
      bfr[ks] = *(const bf16x8*)(w1_t + (size_t)n * 128 + ks * 32 + quad * 8);
    const float bc = par[P_B1 + n];
#pragma unroll
    for (int mt = 0; mt < 2; ++mt) {
      f32x4 acc = (f32x4){0.f, 0.f, 0.f, 0.f};
#pragma unroll
      for (int ks = 0; ks < 4; ++ks) {
        bf16x8 a = *(const bf16x8*)(lnt + (mt * 16 + lcol) * 136 + ks * 32 + quad * 8);
        acc = __builtin_amdgcn_mfma_f32_16x16x32_bf16(a, bfr[ks], acc, 0, 0, 0);
      }
#pragma unroll
      for (int rr = 0; rr < 4; ++rr) {
        int m = mt * 16 + quad * 4 + rr;
        float v = acc[rr] + bc;
        v = 0.5f * v * (1.0f + erff(v * 0.70710678118654752f));
        hbuf[m * 520 + n] = f2b(v);
      }
    }
  }
  __syncthreads();

  f32x4 acc2[2][2];
#pragma unroll
  for (int a = 0; a < 2; ++a)
#pragma unroll
    for (int b = 0; b < 2; ++b) acc2[a][b] = (f32x4){0.f, 0.f, 0.f, 0.f};
#pragma unroll
  for (int np = 0; np < 2; ++np) {
    const int n = np * 64 + wave * 16 + lcol;
    for (int kp = 0; kp < 4; ++kp) {
      bf16x8 bfr[4];
#pragma unroll
      for (int ks = 0; ks < 4; ++ks)
        bfr[ks] = *(const bf16x8*)(w2_t + (size_t)n * 512 + kp * 128 + ks * 32 + quad * 8);
#pragma unroll
      for (int mt = 0; mt < 2; ++mt) {
#pragma unroll
        for (int ks = 0; ks < 4; ++ks) {
          bf16x8 a = *(const bf16x8*)(hbuf + (mt * 16 + lcol) * 520 + kp * 128 +
                                      ks * 32 + quad * 8);
          acc2[np][mt] = __builtin_amdgcn_mfma_f32_16x16x32_bf16(a, bfr[ks], acc2[np][mt], 0, 0, 0);
        }
      }
    }
  }
  __syncthreads();   // hbuf reads done before pout overlays it

  // ---- stage MLP2+bias (f32) -> pout[32][132] overlaying hbuf ----
  float* pout = (float*)hbuf;
#pragma unroll
  for (int np = 0; np < 2; ++np) {
    const int n = np * 64 + wave * 16 + lcol;
    const float bc = par[P_B2 + n];
#pragma unroll
    for (int mt = 0; mt < 2; ++mt)
#pragma unroll
      for (int rr = 0; rr < 4; ++rr)
        pout[(mt * 16 + quad * 4 + rr) * 132 + n] = acc2[np][mt][rr] + bc;
  }
  __syncthreads();

  // ---- coalesced residual + store: 32 contiguous token rows (16 KB) ----
  for (int i = tid; i < 1024; i += 256) {
    int t = i >> 5, c = (i & 31) * 4;
    size_t base = (size_t)(m0 + t) * 128 + c;
    float4 p = *(const float4*)(pout + t * 132 + c);
    if (f32) {
      const float4 xr = *(const float4*)((const float*)out + base);
      float4 ov = make_float4(p.x + xr.x, p.y + xr.y, p.z + xr.z, p.w + xr.w);
      *(float4*)((float*)out + base) = ov;
    } else {
      const ushort4 xr = *(const ushort4*)((const unsigned short*)out + base);
      ushort4 ov;
      ov.x = f2b(p.x + b2f(xr.x)); ov.y = f2b(p.y + b2f(xr.y));
      ov.z = f2b(p.z + b2f(xr.z)); ov.w = f2b(p.w + b2f(xr.w));
      *(ushort4*)((unsigned short*)out + base) = ov;
    }
  }
}

// ---------------- host launch ----------------
extern "C" void kernel_launch(void* const* d_in, const int* in_sizes, int n_in,
                              void* d_out, int out_size, void* d_ws, size_t ws_size,
                              hipStream_t stream) {
  const void* x      = d_in[0];
  const int*  rel    = (const int*)d_in[1];
  const void* rpb    = d_in[2];
  const void* qkv_w  = d_in[3];
  const void* qkv_b  = d_in[4];
  const void* proj_w = d_in[5];
  const void* proj_b = d_in[6];
  const void* ln1_g  = d_in[7];
  const void* ln1_b  = d_in[8];
  const void* ln2_g  = d_in[9];
  const void* ln2_b  = d_in[10];
  const void* w1     = d_in[11];
  const void* b1     = d_in[12];
  const void* w2     = d_in[13];
  const void* b2     = d_in[14];

  char* ws = (char*)d_ws;
  unsigned short* qg   = (unsigned short*)(ws + QG_OFF);
  unsigned short* kg   = (unsigned short*)(ws + KG_OFF);
  unsigned short* vg   = (unsigned short*)(ws + VG_OFF);
  float*          bias = (float*)(ws + BIAS_OFF);
  unsigned short* wq_t = (unsigned short*)(ws + WQ_OFF);
  unsigned short* wp_t = (unsigned short*)(ws + WP_OFF);
  unsigned short* w1_t = (unsigned short*)(ws + W1_OFF);
  unsigned short* w2_t = (unsigned short*)(ws + W2_OFF);
  float*          par  = (float*)(ws + PAR_OFF);
  int*            flag = (int*)(ws + FLAG_OFF);

  detect_kernel<<<1, 256, 0, stream>>>((const uint32_t*)x, flag);
  prep_kernel<<<775, 256, 0, stream>>>(qkv_w, proj_w, w1, w2, ln1_g, ln1_b, ln2_g,
                                       ln2_b, qkv_b, proj_b, b1, b2, flag,
                                       wq_t, wp_t, w1_t, w2_t, par);
  bias_kernel<<<(4 * BIAS_N + 255) / 256, 256, 0, stream>>>(rel, rpb, flag, bias);
  qkv_win_kernel<<<NWIN, 256, 0, stream>>>(x, flag, wq_t, par, qg, kg, vg);
  attn_fused_kernel<<<NWIN, 256, 0, stream>>>(qg, kg, vg, bias, wp_t, par, x, flag, d_out);
  mlp_kernel<<<100352 / 32, 256, 0, stream>>>(w1_t, w2_t, par, flag, d_out);
}

// Round 3
// 431.523 us; speedup vs baseline: 1.0952x; 1.0200x over previous
//
#include <hip/hip_runtime.h>
#include <hip/hip_bf16.h>
#include <cstdint>

#define NWIN   1024
#define NTOK   98
#define BIAS_N 9604   // 98*98

typedef __attribute__((ext_vector_type(8))) short bf16x8;
typedef __attribute__((ext_vector_type(4))) float f32x4;

__device__ __forceinline__ float b2f(unsigned short u) {
  union { uint32_t i; float f; } v; v.i = ((uint32_t)u) << 16; return v.f;
}
__device__ __forceinline__ float b2f_lo(uint32_t u) {
  union { uint32_t i; float f; } v; v.i = u << 16; return v.f;
}
__device__ __forceinline__ float b2f_hi(uint32_t u) {
  union { uint32_t i; float f; } v; v.i = u & 0xffff0000u; return v.f;
}
__device__ __forceinline__ unsigned short f2b(float f) {  // RNE
  union { float f; uint32_t i; } v; v.f = f;
  uint32_t r = v.i + 0x7fffu + ((v.i >> 16) & 1u);
  return (unsigned short)(r >> 16);
}
__device__ __forceinline__ float ldf(const void* p, size_t i, int f32) {
  return f32 ? ((const float*)p)[i] : b2f(((const unsigned short*)p)[i]);
}
__device__ __forceinline__ void stf(void* p, size_t i, int f32, float v) {
  if (f32) ((float*)p)[i] = v;
  else     ((unsigned short*)p)[i] = f2b(v);
}
__device__ __forceinline__ float2 ldf2(const void* p, size_t i, int f32) {  // i even
  if (f32) { const float* q = (const float*)p + i; return make_float2(q[0], q[1]); }
  uint32_t u = *(const uint32_t*)((const unsigned short*)p + i);
  return make_float2(b2f_lo(u), b2f_hi(u));
}

// ws offsets (bytes)
#define QG_OFF   0
#define KG_OFF   25690112
#define VG_OFF   51380224
#define BIAS_OFF 77070336    // f32, 153664 B
#define WQ_OFF   77224000    // bf16 [384][128]
#define WP_OFF   77322304    // bf16 [128][128]
#define W1_OFF   77355072    // bf16 [512][128]
#define W2_OFF   77486144    // bf16 [128][512]
#define PAR_OFF  77617216    // f32 x 1664
#define FLAG_OFF 77623872
// param layout (float idx)
#define P_LN1G 0
#define P_LN1B 128
#define P_LN2G 256
#define P_LN2B 384
#define P_QKVB 512
#define P_PROJB 896
#define P_B1  1024
#define P_B2  1536

// ---------------- K0: detect float-tensor storage format ----------------
__global__ __launch_bounds__(256) void detect_kernel(const uint32_t* __restrict__ xw,
                                                     int* __restrict__ flag) {
  __shared__ int cnt;
  if (threadIdx.x == 0) cnt = 0;
  __syncthreads();
  uint32_t w = xw[threadIdx.x];
  int e = (w >> 23) & 0xFF;
  if (e >= 112 && e <= 134) atomicAdd(&cnt, 1);
  __syncthreads();
  if (threadIdx.x == 0) *flag = (cnt >= 128) ? 1 : 0;
}

// ---------------- K1: weight transpose->bf16 + param->f32 ----------------
__global__ __launch_bounds__(256) void prep_kernel(
    const void* __restrict__ qkvw, const void* __restrict__ projw,
    const void* __restrict__ w1, const void* __restrict__ w2,
    const void* __restrict__ ln1g, const void* __restrict__ ln1b,
    const void* __restrict__ ln2g, const void* __restrict__ ln2b,
    const void* __restrict__ qkvb, const void* __restrict__ projb,
    const void* __restrict__ b1, const void* __restrict__ b2,
    const int* __restrict__ flag,
    unsigned short* __restrict__ wq_t, unsigned short* __restrict__ wp_t,
    unsigned short* __restrict__ w1_t, unsigned short* __restrict__ w2_t,
    float* __restrict__ par) {
  const int f32 = *flag;
  int idx = blockIdx.x * 256 + threadIdx.x;
  if (idx < 49152) {
    int n = idx >> 7, k = idx & 127;
    wq_t[idx] = f2b(ldf(qkvw, (size_t)k * 384 + n, f32));
  } else if ((idx -= 49152) < 16384) {
    int n = idx >> 7, k = idx & 127;
    wp_t[idx] = f2b(ldf(projw, (size_t)k * 128 + n, f32));
  } else if ((idx -= 16384) < 65536) {
    int n = idx >> 7, k = idx & 127;
    w1_t[idx] = f2b(ldf(w1, (size_t)k * 512 + n, f32));
  } else if ((idx -= 65536) < 65536) {
    int n = idx >> 9, k = idx & 511;
    w2_t[idx] = f2b(ldf(w2, (size_t)k * 128 + n, f32));
  } else if ((idx -= 65536) < 1664) {
    float v;
    if      (idx < 128)  v = ldf(ln1g, idx, f32);
    else if (idx < 256)  v = ldf(ln1b, idx - 128, f32);
    else if (idx < 384)  v = ldf(ln2g, idx - 256, f32);
    else if (idx < 512)  v = ldf(ln2b, idx - 384, f32);
    else if (idx < 896)  v = ldf(qkvb, idx - 512, f32);
    else if (idx < 1024) v = ldf(projb, idx - 896, f32);
    else if (idx < 1536) v = ldf(b1, idx - 1024, f32);
    else                 v = ldf(b2, idx - 1536, f32);
    par[idx] = v;
  }
}

// ---------------- K2: bias[h][i*98+j] = table[rel_idx[i,j]][h] ----------------
__global__ __launch_bounds__(256) void bias_kernel(const int* __restrict__ rel_idx,
                                                   const void* __restrict__ tbl,
                                                   const int* __restrict__ flag,
                                                   float* __restrict__ bias) {
  const int f32 = *flag;
  int i = blockIdx.x * 256 + threadIdx.x;
  if (i >= 4 * BIAS_N) return;
  int h = i / BIAS_N, ij = i % BIAS_N;
  bias[i] = ldf(tbl, (size_t)rel_idx[ij] * 4 + h, f32);
}

// ---------------- K3: per-window LN1+gather + QKV MFMA ----------------
__global__ __launch_bounds__(256) void qkv_win_kernel(
    const void* __restrict__ x, const int* __restrict__ flag,
    const unsigned short* __restrict__ wq_t, const float* __restrict__ par,
    unsigned short* __restrict__ qg, unsigned short* __restrict__ kg,
    unsigned short* __restrict__ vg) {
  __shared__ unsigned short lnx[112 * 136];
  const int f32 = *flag;
  const int tid = threadIdx.x, wave = tid >> 6, lane = tid & 63;
  const int quad = lane >> 4, lcol = lane & 15;
  const int win = blockIdx.x;
  const int bb = win >> 8, r = win & 255;
  const int wd = r >> 6, r2 = r & 63, wh = r2 >> 3, ww = r2 & 7;

  for (int t = wave; t < NTOK; t += 4) {
    int td = t / 49, r3 = t % 49, th = r3 / 7, tw = r3 % 7;
    int sd = (wd * 2 + td + 1) & 7;
    int sh = (wh * 7 + th + 3) % 56;
    int sw = (ww * 7 + tw + 3) % 56;
    size_t src = ((((size_t)bb * 8 + sd) * 56 + sh) * 56 + sw) * 128;
    int c0 = lane * 2;
    float2 f = ldf2(x, src + c0, f32);
    float s = f.x + f.y, ss = f.x * f.x + f.y * f.y;
#pragma unroll
    for (int off = 32; off >= 1; off >>= 1) { s += __shfl_xor(s, off); ss += __shfl_xor(ss, off); }
    float mu = s * (1.0f / 128.0f);
    float var = ss * (1.0f / 128.0f) - mu * mu;
    float rs = rsqrtf(var + 1e-5f);
    float y0 = (f.x - mu) * rs * par[P_LN1G + c0] + par[P_LN1B + c0];
    float y1 = (f.y - mu) * rs * par[P_LN1G + c0 + 1] + par[P_LN1B + c0 + 1];
    *(uint32_t*)(lnx + t * 136 + c0) = (uint32_t)f2b(y0) | ((uint32_t)f2b(y1) << 16);
  }
  for (int i = tid; i < 14 * 68; i += 256) {
    int rr = i / 68, c = i % 68;
    *(uint32_t*)(lnx + (98 + rr) * 136 + c * 2) = 0u;
  }
  __syncthreads();

  for (int p = 0; p < 6; ++p) {
    const int n = p * 64 + wave * 16 + lcol;
    bf16x8 bfr[4];
#pragma unroll
    for (int ks = 0; ks < 4; ++ks)
      bfr[ks] = *(const bf16x8*)(wq_t + (size_t)n * 128 + ks * 32 + quad * 8);
    const int region = n >> 7, cc = n & 127, head = cc >> 5, d = cc & 31;
    unsigned short* dst = (region == 0 ? qg : (region == 1 ? kg : vg)) +
                          (((size_t)win * 4 + head) * NTOK) * 32 + d;
    const float bc = par[P_QKVB + n];
    const float scale = region == 0 ? 0.17677669529663687f : 1.0f;
    for (int mt = 0; mt < 7; ++mt) {
      f32x4 acc = (f32x4){0.f, 0.f, 0.f, 0.f};
#pragma unroll
      for (int ks = 0; ks < 4; ++ks) {
        bf16x8 a = *(const bf16x8*)(lnx + (mt * 16 + lcol) * 136 + ks * 32 + quad * 8);
        acc = __builtin_amdgcn_mfma_f32_16x16x32_bf16(a, bfr[ks], acc, 0, 0, 0);
      }
#pragma unroll
      for (int rr = 0; rr < 4; ++rr) {
        int m = mt * 16 + quad * 4 + rr;
        if (m < NTOK) dst[m * 32] = f2b((acc[rr] + bc) * scale);
      }
    }
  }
}

// ---------------- K4: fused MFMA attention + proj + residual, 1 block/window ----------------
__global__ __launch_bounds__(256) void attn_fused_kernel(
    const unsigned short* __restrict__ qg, const unsigned short* __restrict__ kg,
    const unsigned short* __restrict__ vg, const float* __restrict__ bias,
    const unsigned short* __restrict__ wp_t, const float* __restrict__ par,
    const void* __restrict__ x, const int* __restrict__ flag,
    void* __restrict__ out) {
  __shared__ __align__(16) unsigned short smem[26112];  // 52224 B
  const int f32 = *flag;
  const int tid = threadIdx.x, wave = tid >> 6, lane = tid & 63;
  const int quad = lane >> 4, lcol = lane & 15;
  const int win = blockIdx.x, h = wave;
  const size_t hb = (((size_t)win * 4 + h) * NTOK) * 32;

  unsigned short* vth = smem + h * (32 * 136);
  unsigned short* plh = smem + 17408 + h * (16 * 136);

  // ---- stage V^T (vt[d][j] = V[j][d]), zero pads; all wave-private, no barrier ----
  {
    const uint32_t* vsrc = (const uint32_t*)(vg + hb);
    for (int idx = lane; idx < NTOK * 16; idx += 64) {
      int j = idx >> 4, dp = idx & 15;
      uint32_t u = vsrc[idx];
      vth[(2 * dp) * 136 + j]     = (unsigned short)(u & 0xffffu);
      vth[(2 * dp + 1) * 136 + j] = (unsigned short)(u >> 16);
    }
    for (int idx = lane; idx < 32 * 30; idx += 64) {
      int d = idx / 30, c = 98 + idx % 30;
      vth[d * 136 + c] = 0;
    }
    for (int idx = lane; idx < 16 * 16; idx += 64) {
      int rr = idx >> 4, c = 112 + (idx & 15);
      plh[rr * 136 + c] = 0;
    }
  }

  // ---- Q/K fragments direct from global (rows clamped at 97; pad rows discarded) ----
  bf16x8 aq[7], bk[7];
#pragma unroll
  for (int t = 0; t < 7; ++t) {
    int row = min(t * 16 + lcol, NTOK - 1);
    aq[t] = *(const bf16x8*)(qg + hb + (size_t)row * 32 + quad * 8);
    bk[t] = *(const bf16x8*)(kg + hb + (size_t)row * 32 + quad * 8);
  }

  const float* bh = bias + h * BIAS_N;
  f32x4 o[7][2];
  for (int mt = 0; mt < 7; ++mt) {
    // scores S[i][j], i = mt*16+quad*4+r, j = nt*16+lcol
    f32x4 s[7];
#pragma unroll
    for (int nt = 0; nt < 7; ++nt)
      s[nt] = __builtin_amdgcn_mfma_f32_16x16x32_bf16(aq[mt], bk[nt],
                                                      (f32x4){0.f, 0.f, 0.f, 0.f}, 0, 0, 0);
    const int ib = mt * 16 + quad * 4;
#pragma unroll
    for (int nt = 0; nt < 7; ++nt) {
      int j = nt * 16 + lcol;
      bool jv = j < NTOK;
#pragma unroll
      for (int r = 0; r < 4; ++r) {
        int ic = min(ib + r, NTOK - 1);
        s[nt][r] = jv ? (s[nt][r] + bh[ic * NTOK + j]) : -3.0e38f;
      }
    }
    // row softmax: local over nt, then shfl_xor across the 16-lane column group
    float mx[4], sum[4], inv[4];
#pragma unroll
    for (int r = 0; r < 4; ++r) {
      float m = s[0][r];
#pragma unroll
      for (int nt = 1; nt < 7; ++nt) m = fmaxf(m, s[nt][r]);
      mx[r] = m;
    }
#pragma unroll
    for (int off = 1; off < 16; off <<= 1)
#pragma unroll
      for (int r = 0; r < 4; ++r) mx[r] = fmaxf(mx[r], __shfl_xor(mx[r], off));
#pragma unroll
    for (int r = 0; r < 4; ++r) sum[r] = 0.f;
#pragma unroll
    for (int nt = 0; nt < 7; ++nt)
#pragma unroll
      for (int r = 0; r < 4; ++r) {
        float e = __expf(s[nt][r] - mx[r]);
        s[nt][r] = e; sum[r] += e;
      }
#pragma unroll
    for (int off = 1; off < 16; off <<= 1)
#pragma unroll
      for (int r = 0; r < 4; ++r) sum[r] += __shfl_xor(sum[r], off);
#pragma unroll
    for (int r = 0; r < 4; ++r) inv[r] = 1.0f / sum[r];
    // write P (bf16) to own LDS tile in A-layout source form [i][j] (wave-private)
#pragma unroll
    for (int nt = 0; nt < 7; ++nt)
#pragma unroll
      for (int r = 0; r < 4; ++r)
        plh[(quad * 4 + r) * 136 + nt * 16 + lcol] = f2b(s[nt][r] * inv[r]);
    // PV: A = P tile (K=128 padded with zeros), B = V^T  (no block barrier: same-wave dep)
#pragma unroll
    for (int n2 = 0; n2 < 2; ++n2) {
      f32x4 acc = (f32x4){0.f, 0.f, 0.f, 0.f};
#pragma unroll
      for (int kp = 0; kp < 4; ++kp) {
        bf16x8 a = *(const bf16x8*)(plh + lcol * 136 + kp * 32 + quad * 8);
        bf16x8 b = *(const bf16x8*)(vth + (n2 * 16 + lcol) * 136 + kp * 32 + quad * 8);
        acc = __builtin_amdgcn_mfma_f32_16x16x32_bf16(a, b, acc, 0, 0, 0);
      }
      o[mt][n2] = acc;
    }
  }
  __syncthreads();   // all waves' PV reads done before olds overlays vt/pl

  // ---- attn-out -> LDS [112][136], full 128 channels ----
  unsigned short* olds = smem;
#pragma unroll
  for (int mt = 0; mt < 7; ++mt)
#pragma unroll
    for (int n2 = 0; n2 < 2; ++n2)
#pragma unroll
      for (int r = 0; r < 4; ++r)
        olds[(mt * 16 + quad * 4 + r) * 136 + h * 32 + n2 * 16 + lcol] = f2b(o[mt][n2][r]);
  __syncthreads();

  // ---- proj into registers ----
  f32x4 pr[2][7];
  for (int t2 = 0; t2 < 2; ++t2) {
    const int n = (h * 2 + t2) * 16 + lcol;
    bf16x8 bw[4];
#pragma unroll
    for (int kp = 0; kp < 4; ++kp)
      bw[kp] = *(const bf16x8*)(wp_t + (size_t)n * 128 + kp * 32 + quad * 8);
    for (int mt = 0; mt < 7; ++mt) {
      f32x4 acc = (f32x4){0.f, 0.f, 0.f, 0.f};
#pragma unroll
      for (int kp = 0; kp < 4; ++kp) {
        bf16x8 a = *(const bf16x8*)(olds + (mt * 16 + lcol) * 136 + kp * 32 + quad * 8);
        acc = __builtin_amdgcn_mfma_f32_16x16x32_bf16(a, bw[kp], acc, 0, 0, 0);
      }
      pr[t2][mt] = acc;
    }
  }
  __syncthreads();   // all olds reads done before pout overlays smem

  // ---- stage proj+bias (f32) -> pout[98][132] ----
  float* pout = (float*)smem;
  for (int t2 = 0; t2 < 2; ++t2) {
    const int n = (h * 2 + t2) * 16 + lcol;
    const float bc = par[P_PROJB + n];
#pragma unroll
    for (int mt = 0; mt < 7; ++mt)
#pragma unroll
      for (int r = 0; r < 4; ++r) {
        int m = mt * 16 + quad * 4 + r;
        if (m < NTOK) pout[m * 132 + n] = pr[t2][mt][r] + bc;
      }
  }
  __syncthreads();

  // ---- coalesced residual + store: one 512B token row per 32-thread group ----
  const int bb = win >> 8, rW = win & 255;
  const int wd = rW >> 6, r2 = rW & 63, wh = r2 >> 3, ww = r2 & 7;
  const int c = (tid & 31) * 4;
  for (int m = tid >> 5; m < NTOK; m += 8) {
    int td = m / 49, r3 = m % 49, th = r3 / 7, tw = r3 % 7;
    int sd = (wd * 2 + td + 1) & 7;
    int sh = (wh * 7 + th + 3) % 56;
    int sw = (ww * 7 + tw + 3) % 56;
    size_t base = ((((size_t)bb * 8 + sd) * 56 + sh) * 56 + sw) * 128 + c;
    float4 p = *(const float4*)(pout + m * 132 + c);
    if (f32) {
      const float4 xr = *(const float4*)((const float*)x + base);
      float4 ov = make_float4(p.x + xr.x, p.y + xr.y, p.z + xr.z, p.w + xr.w);
      *(float4*)((float*)out + base) = ov;
    } else {
      const ushort4 xr = *(const ushort4*)((const unsigned short*)x + base);
      ushort4 ov;
      ov.x = f2b(p.x + b2f(xr.x)); ov.y = f2b(p.y + b2f(xr.y));
      ov.z = f2b(p.z + b2f(xr.z)); ov.w = f2b(p.w + b2f(xr.w));
      *(ushort4*)((unsigned short*)out + base) = ov;
    }
  }
}

// ---------------- K5: LN2 + MLP1(gelu) + MLP2 + residual ----------------
// Changes vs r2: split-K through hbuf — hidden dim processed in 2 halves of 256 so
// hbuf shrinks 32x520 -> 32x264 shorts. LDS 41984 -> 25600 B => 3 -> 6 WG/CU
// (occupancy 30% -> ~65%+). acc2 accumulates across halves in registers.
__global__ __launch_bounds__(256) void mlp_kernel(
    const unsigned short* __restrict__ w1_t, const unsigned short* __restrict__ w2_t,
    const float* __restrict__ par, const int* __restrict__ flag,
    void* __restrict__ out) {
  __shared__ __align__(16) unsigned short lnt[32 * 136];   //  8704 B
  __shared__ __align__(16) unsigned short hbuf[32 * 264];  // 16896 B; pout (32x132 f32) overlays
  const int f32 = *flag;
  const int tid = threadIdx.x, wave = tid >> 6, lane = tid & 63;
  const int quad = lane >> 4, lcol = lane & 15;
  const int m0 = blockIdx.x * 32;

  for (int t = wave; t < 32; t += 4) {
    int c0 = lane * 2;
    float2 f = ldf2(out, (size_t)(m0 + t) * 128 + c0, f32);
    float s = f.x + f.y, ss = f.x * f.x + f.y * f.y;
#pragma unroll
    for (int off = 32; off >= 1; off >>= 1) { s += __shfl_xor(s, off); ss += __shfl_xor(ss, off); }
    float mu = s * (1.0f / 128.0f);
    float var = ss * (1.0f / 128.0f) - mu * mu;
    float rs = rsqrtf(var + 1e-5f);
    float y0 = (f.x - mu) * rs * par[P_LN2G + c0] + par[P_LN2B + c0];
    float y1 = (f.y - mu) * rs * par[P_LN2G + c0 + 1] + par[P_LN2B + c0 + 1];
    *(uint32_t*)(lnt + t * 136 + c0) = (uint32_t)f2b(y0) | ((uint32_t)f2b(y1) << 16);
  }
  __syncthreads();

  f32x4 acc2[2][2];
#pragma unroll
  for (int a = 0; a < 2; ++a)
#pragma unroll
    for (int b = 0; b < 2; ++b) acc2[a][b] = (f32x4){0.f, 0.f, 0.f, 0.f};

  for (int g = 0; g < 2; ++g) {
    // ---- GEMM1 + gelu for hidden n in [g*256, g*256+256) ----
    for (int p = 0; p < 4; ++p) {
      const int nl = p * 64 + wave * 16 + lcol;      // local hidden idx in [0,256)
      const int n = g * 256 + nl;
      bf16x8 bfr[4];
#pragma unroll
      for (int ks = 0; ks < 4; ++ks)
        bfr[ks] = *(const bf16x8*)(w1_t + (size_t)n * 128 + ks * 32 + quad * 8);
      const float bc = par[P_B1 + n];
#pragma unroll
      for (int mt = 0; mt < 2; ++mt) {
        f32x4 acc = (f32x4){0.f, 0.f, 0.f, 0.f};
#pragma unroll
        for (int ks = 0; ks < 4; ++ks) {
          bf16x8 a = *(const bf16x8*)(lnt + (mt * 16 + lcol) * 136 + ks * 32 + quad * 8);
          acc = __builtin_amdgcn_mfma_f32_16x16x32_bf16(a, bfr[ks], acc, 0, 0, 0);
        }
#pragma unroll
        for (int rr = 0; rr < 4; ++rr) {
          int m = mt * 16 + quad * 4 + rr;
          float v = acc[rr] + bc;
          v = 0.5f * v * (1.0f + erff(v * 0.70710678118654752f));
          hbuf[m * 264 + nl] = f2b(v);
        }
      }
    }
    __syncthreads();   // hbuf fully written for this half

    // ---- GEMM2 partial over this K=256 half, accumulate into acc2 ----
#pragma unroll
    for (int np = 0; np < 2; ++np) {
      const int n = np * 64 + wave * 16 + lcol;
      for (int kp = 0; kp < 2; ++kp) {
        bf16x8 bfr[4];
#pragma unroll
        for (int ks = 0; ks < 4; ++ks)
          bfr[ks] = *(const bf16x8*)(w2_t + (size_t)n * 512 + g * 256 + kp * 128 +
                                     ks * 32 + quad * 8);
#pragma unroll
        for (int mt = 0; mt < 2; ++mt) {
#pragma unroll
          for (int ks = 0; ks < 4; ++ks) {
            bf16x8 a = *(const bf16x8*)(hbuf + (mt * 16 + lcol) * 264 + kp * 128 +
                                        ks * 32 + quad * 8);
            acc2[np][mt] = __builtin_amdgcn_mfma_f32_16x16x32_bf16(a, bfr[ks], acc2[np][mt], 0, 0, 0);
          }
        }
      }
    }
    __syncthreads();   // hbuf reads done before next half overwrites (or pout overlays)
  }

  // ---- stage MLP2+bias (f32) -> pout[32][132] overlaying hbuf ----
  float* pout = (float*)hbuf;
#pragma unroll
  for (int np = 0; np < 2; ++np) {
    const int n = np * 64 + wave * 16 + lcol;
    const float bc = par[P_B2 + n];
#pragma unroll
    for (int mt = 0; mt < 2; ++mt)
#pragma unroll
      for (int rr = 0; rr < 4; ++rr)
        pout[(mt * 16 + quad * 4 + rr) * 132 + n] = acc2[np][mt][rr] + bc;
  }
  __syncthreads();

  // ---- coalesced residual + store: 32 contiguous token rows (16 KB) ----
  for (int i = tid; i < 1024; i += 256) {
    int t = i >> 5, c = (i & 31) * 4;
    size_t base = (size_t)(m0 + t) * 128 + c;
    float4 p = *(const float4*)(pout + t * 132 + c);
    if (f32) {
      const float4 xr = *(const float4*)((const float*)out + base);
      float4 ov = make_float4(p.x + xr.x, p.y + xr.y, p.z + xr.z, p.w + xr.w);
      *(float4*)((float*)out + base) = ov;
    } else {
      const ushort4 xr = *(const ushort4*)((const unsigned short*)out + base);
      ushort4 ov;
      ov.x = f2b(p.x + b2f(xr.x)); ov.y = f2b(p.y + b2f(xr.y));
      ov.z = f2b(p.z + b2f(xr.z)); ov.w = f2b(p.w + b2f(xr.w));
      *(ushort4*)((unsigned short*)out + base) = ov;
    }
  }
}

// ---------------- host launch ----------------
extern "C" void kernel_launch(void* const* d_in, const int* in_sizes, int n_in,
                              void* d_out, int out_size, void* d_ws, size_t ws_size,
                              hipStream_t stream) {
  const void* x      = d_in[0];
  const int*  rel    = (const int*)d_in[1];
  const void* rpb    = d_in[2];
  const void* qkv_w  = d_in[3];
  const void* qkv_b  = d_in[4];
  const void* proj_w = d_in[5];
  const void* proj_b = d_in[6];
  const void* ln1_g  = d_in[7];
  const void* ln1_b  = d_in[8];
  const void* ln2_g  = d_in[9];
  const void* ln2_b  = d_in[10];
  const void* w1     = d_in[11];
  const void* b1     = d_in[12];
  const void* w2     = d_in[13];
  const void* b2     = d_in[14];

  char* ws = (char*)d_ws;
  unsigned short* qg   = (unsigned short*)(ws + QG_OFF);
  unsigned short* kg   = (unsigned short*)(ws + KG_OFF);
  unsigned short* vg   = (unsigned short*)(ws + VG_OFF);
  float*          bias = (float*)(ws + BIAS_OFF);
  unsigned short* wq_t = (unsigned short*)(ws + WQ_OFF);
  unsigned short* wp_t = (unsigned short*)(ws + WP_OFF);
  unsigned short* w1_t = (unsigned short*)(ws + W1_OFF);
  unsigned short* w2_t = (unsigned short*)(ws + W2_OFF);
  float*          par  = (float*)(ws + PAR_OFF);
  int*            flag = (int*)(ws + FLAG_OFF);

  detect_kernel<<<1, 256, 0, stream>>>((const uint32_t*)x, flag);
  prep_kernel<<<775, 256, 0, stream>>>(qkv_w, proj_w, w1, w2, ln1_g, ln1_b, ln2_g,
                                       ln2_b, qkv_b, proj_b, b1, b2, flag,
                                       wq_t, wp_t, w1_t, w2_t, par);
  bias_kernel<<<(4 * BIAS_N + 255) / 256, 256, 0, stream>>>(rel, rpb, flag, bias);
  qkv_win_kernel<<<NWIN, 256, 0, stream>>>(x, flag, wq_t, par, qg, kg, vg);
  attn_fused_kernel<<<NWIN, 256, 0, stream>>>(qg, kg, vg, bias, wp_t, par, x, flag, d_out);
  mlp_kernel<<<100352 / 32, 256, 0, stream>>>(w1_t, w2_t, par, flag, d_out);
}

// Round 4
// 404.073 us; speedup vs baseline: 1.1696x; 1.0679x over previous
//
#include <hip/hip_runtime.h>
#include <hip/hip_bf16.h>
#include <cstdint>

#define NWIN   1024
#define NTOK   98
#define BIAS_N 9604   // 98*98

typedef __attribute__((ext_vector_type(8))) short bf16x8;
typedef __attribute__((ext_vector_type(4))) float f32x4;

__device__ __forceinline__ float b2f(unsigned short u) {
  union { uint32_t i; float f; } v; v.i = ((uint32_t)u) << 16; return v.f;
}
__device__ __forceinline__ float b2f_lo(uint32_t u) {
  union { uint32_t i; float f; } v; v.i = u << 16; return v.f;
}
__device__ __forceinline__ float b2f_hi(uint32_t u) {
  union { uint32_t i; float f; } v; v.i = u & 0xffff0000u; return v.f;
}
__device__ __forceinline__ unsigned short f2b(float f) {  // RNE
  union { float f; uint32_t i; } v; v.f = f;
  uint32_t r = v.i + 0x7fffu + ((v.i >> 16) & 1u);
  return (unsigned short)(r >> 16);
}
__device__ __forceinline__ float ldf(const void* p, size_t i, int f32) {
  return f32 ? ((const float*)p)[i] : b2f(((const unsigned short*)p)[i]);
}
__device__ __forceinline__ void stf(void* p, size_t i, int f32, float v) {
  if (f32) ((float*)p)[i] = v;
  else     ((unsigned short*)p)[i] = f2b(v);
}
__device__ __forceinline__ float2 ldf2(const void* p, size_t i, int f32) {  // i even
  if (f32) { const float* q = (const float*)p + i; return make_float2(q[0], q[1]); }
  uint32_t u = *(const uint32_t*)((const unsigned short*)p + i);
  return make_float2(b2f_lo(u), b2f_hi(u));
}

// ws offsets (bytes)
#define QG_OFF   0
#define KG_OFF   25690112
#define VGT_OFF  51380224    // bf16 [1024][4][32][112] transposed V
#define ZPAD_OFF 80740352    // 8192 B zeros (guards V-frag over-reads at region end)
#define BIAS_OFF 80748544    // f32, 153664 B
#define WQ_OFF   80902208    // bf16 [384][128]
#define WP_OFF   81000512    // bf16 [128][128]
#define W1_OFF   81033280    // bf16 [512][128]
#define W2_OFF   81164352    // bf16 [128][512]
#define PAR_OFF  81295424    // f32 x 1664
#define FLAG_OFF 81302080
// param layout (float idx)
#define P_LN1G 0
#define P_LN1B 128
#define P_LN2G 256
#define P_LN2B 384
#define P_QKVB 512
#define P_PROJB 896
#define P_B1  1024
#define P_B2  1536

// ---------------- K0: detect float-tensor storage format ----------------
__global__ __launch_bounds__(256) void detect_kernel(const uint32_t* __restrict__ xw,
                                                     int* __restrict__ flag) {
  __shared__ int cnt;
  if (threadIdx.x == 0) cnt = 0;
  __syncthreads();
  uint32_t w = xw[threadIdx.x];
  int e = (w >> 23) & 0xFF;
  if (e >= 112 && e <= 134) atomicAdd(&cnt, 1);
  __syncthreads();
  if (threadIdx.x == 0) *flag = (cnt >= 128) ? 1 : 0;
}

// ---------------- K1: weight transpose->bf16 + param->f32 + vgt tail pad ----------------
__global__ __launch_bounds__(256) void prep_kernel(
    const void* __restrict__ qkvw, const void* __restrict__ projw,
    const void* __restrict__ w1, const void* __restrict__ w2,
    const void* __restrict__ ln1g, const void* __restrict__ ln1b,
    const void* __restrict__ ln2g, const void* __restrict__ ln2b,
    const void* __restrict__ qkvb, const void* __restrict__ projb,
    const void* __restrict__ b1, const void* __restrict__ b2,
    const int* __restrict__ flag,
    unsigned short* __restrict__ wq_t, unsigned short* __restrict__ wp_t,
    unsigned short* __restrict__ w1_t, unsigned short* __restrict__ w2_t,
    float* __restrict__ par, unsigned short* __restrict__ zpad) {
  const int f32 = *flag;
  int idx = blockIdx.x * 256 + threadIdx.x;
  if (idx < 49152) {
    int n = idx >> 7, k = idx & 127;
    wq_t[idx] = f2b(ldf(qkvw, (size_t)k * 384 + n, f32));
  } else if ((idx -= 49152) < 16384) {
    int n = idx >> 7, k = idx & 127;
    wp_t[idx] = f2b(ldf(projw, (size_t)k * 128 + n, f32));
  } else if ((idx -= 16384) < 65536) {
    int n = idx >> 7, k = idx & 127;
    w1_t[idx] = f2b(ldf(w1, (size_t)k * 512 + n, f32));
  } else if ((idx -= 65536) < 65536) {
    int n = idx >> 9, k = idx & 511;
    w2_t[idx] = f2b(ldf(w2, (size_t)k * 128 + n, f32));
  } else if ((idx -= 65536) < 1664) {
    float v;
    if      (idx < 128)  v = ldf(ln1g, idx, f32);
    else if (idx < 256)  v = ldf(ln1b, idx - 128, f32);
    else if (idx < 384)  v = ldf(ln2g, idx - 256, f32);
    else if (idx < 512)  v = ldf(ln2b, idx - 384, f32);
    else if (idx < 896)  v = ldf(qkvb, idx - 512, f32);
    else if (idx < 1024) v = ldf(projb, idx - 896, f32);
    else if (idx < 1536) v = ldf(b1, idx - 1024, f32);
    else                 v = ldf(b2, idx - 1536, f32);
    par[idx] = v;
  } else if ((idx -= 1664) < 4096) {
    zpad[idx] = 0;
  }
}

// ---------------- K2: bias[h][i*98+j] = table[rel_idx[i,j]][h] ----------------
__global__ __launch_bounds__(256) void bias_kernel(const int* __restrict__ rel_idx,
                                                   const void* __restrict__ tbl,
                                                   const int* __restrict__ flag,
                                                   float* __restrict__ bias) {
  const int f32 = *flag;
  int i = blockIdx.x * 256 + threadIdx.x;
  if (i >= 4 * BIAS_N) return;
  int h = i / BIAS_N, ij = i % BIAS_N;
  bias[i] = ldf(tbl, (size_t)rel_idx[ij] * 4 + h, f32);
}

// ---------------- K3: per-window LN1+gather + QKV MFMA ----------------
// V region now written TRANSPOSED: vgt[win][h][d][112] with rows j=98..111 zeroed
// (contiguous 8B stores per lane vs previous 2B x stride-64B scatter).
__global__ __launch_bounds__(256) void qkv_win_kernel(
    const void* __restrict__ x, const int* __restrict__ flag,
    const unsigned short* __restrict__ wq_t, const float* __restrict__ par,
    unsigned short* __restrict__ qg, unsigned short* __restrict__ kg,
    unsigned short* __restrict__ vgt) {
  __shared__ unsigned short lnx[112 * 136];
  const int f32 = *flag;
  const int tid = threadIdx.x, wave = tid >> 6, lane = tid & 63;
  const int quad = lane >> 4, lcol = lane & 15;
  const int win = blockIdx.x;
  const int bb = win >> 8, r = win & 255;
  const int wd = r >> 6, r2 = r & 63, wh = r2 >> 3, ww = r2 & 7;

  for (int t = wave; t < NTOK; t += 4) {
    int td = t / 49, r3 = t % 49, th = r3 / 7, tw = r3 % 7;
    int sd = (wd * 2 + td + 1) & 7;
    int sh = (wh * 7 + th + 3) % 56;
    int sw = (ww * 7 + tw + 3) % 56;
    size_t src = ((((size_t)bb * 8 + sd) * 56 + sh) * 56 + sw) * 128;
    int c0 = lane * 2;
    float2 f = ldf2(x, src + c0, f32);
    float s = f.x + f.y, ss = f.x * f.x + f.y * f.y;
#pragma unroll
    for (int off = 32; off >= 1; off >>= 1) { s += __shfl_xor(s, off); ss += __shfl_xor(ss, off); }
    float mu = s * (1.0f / 128.0f);
    float var = ss * (1.0f / 128.0f) - mu * mu;
    float rs = rsqrtf(var + 1e-5f);
    float y0 = (f.x - mu) * rs * par[P_LN1G + c0] + par[P_LN1B + c0];
    float y1 = (f.y - mu) * rs * par[P_LN1G + c0 + 1] + par[P_LN1B + c0 + 1];
    *(uint32_t*)(lnx + t * 136 + c0) = (uint32_t)f2b(y0) | ((uint32_t)f2b(y1) << 16);
  }
  for (int i = tid; i < 14 * 68; i += 256) {
    int rr = i / 68, c = i % 68;
    *(uint32_t*)(lnx + (98 + rr) * 136 + c * 2) = 0u;
  }
  __syncthreads();

  for (int p = 0; p < 6; ++p) {
    const int n = p * 64 + wave * 16 + lcol;
    bf16x8 bfr[4];
#pragma unroll
    for (int ks = 0; ks < 4; ++ks)
      bfr[ks] = *(const bf16x8*)(wq_t + (size_t)n * 128 + ks * 32 + quad * 8);
    const int region = n >> 7, cc = n & 127, head = cc >> 5, d = cc & 31;
    const float bc = par[P_QKVB + n];
    if (region < 2) {
      unsigned short* dst = (region == 0 ? qg : kg) +
                            (((size_t)win * 4 + head) * NTOK) * 32 + d;
      const float scale = region == 0 ? 0.17677669529663687f : 1.0f;
      for (int mt = 0; mt < 7; ++mt) {
        f32x4 acc = (f32x4){0.f, 0.f, 0.f, 0.f};
#pragma unroll
        for (int ks = 0; ks < 4; ++ks) {
          bf16x8 a = *(const bf16x8*)(lnx + (mt * 16 + lcol) * 136 + ks * 32 + quad * 8);
          acc = __builtin_amdgcn_mfma_f32_16x16x32_bf16(a, bfr[ks], acc, 0, 0, 0);
        }
#pragma unroll
        for (int rr = 0; rr < 4; ++rr) {
          int m = mt * 16 + quad * 4 + rr;
          if (m < NTOK) dst[m * 32] = f2b((acc[rr] + bc) * scale);
        }
      }
    } else {
      // V: transposed store vgt[(win*4+head)*32 + d][m], 8B contiguous, pad zeroed
      unsigned short* dstv = vgt + (((size_t)win * 4 + head) * 32 + d) * 112;
      for (int mt = 0; mt < 7; ++mt) {
        f32x4 acc = (f32x4){0.f, 0.f, 0.f, 0.f};
#pragma unroll
        for (int ks = 0; ks < 4; ++ks) {
          bf16x8 a = *(const bf16x8*)(lnx + (mt * 16 + lcol) * 136 + ks * 32 + quad * 8);
          acc = __builtin_amdgcn_mfma_f32_16x16x32_bf16(a, bfr[ks], acc, 0, 0, 0);
        }
        ushort4 w;
        int m0 = mt * 16 + quad * 4;
        w.x = (m0 + 0 < NTOK) ? f2b(acc[0] + bc) : (unsigned short)0;
        w.y = (m0 + 1 < NTOK) ? f2b(acc[1] + bc) : (unsigned short)0;
        w.z = (m0 + 2 < NTOK) ? f2b(acc[2] + bc) : (unsigned short)0;
        w.w = (m0 + 3 < NTOK) ? f2b(acc[3] + bc) : (unsigned short)0;
        *(ushort4*)(dstv + m0) = w;
      }
    }
  }
}

// ---------------- K4: fused MFMA attention + proj + residual, 1 block/window ----------------
// Changes vs r3: V^T LDS staging eliminated (PV B-frags read directly from vgt,
// L2-hot ~28KB/window). LDS 52224 -> 30464 B => 3 -> 4 WG/CU. pout staged in two
// 56-row passes to fit. __launch_bounds__(256,4) pins 4 blocks/CU.
__global__ __launch_bounds__(256, 4) void attn_fused_kernel(
    const unsigned short* __restrict__ qg, const unsigned short* __restrict__ kg,
    const unsigned short* __restrict__ vgt, const float* __restrict__ bias,
    const unsigned short* __restrict__ wp_t, const float* __restrict__ par,
    const void* __restrict__ x, const int* __restrict__ flag,
    void* __restrict__ out) {
  __shared__ __align__(16) unsigned short smem[15232];   // 30464 B
  const int f32 = *flag;
  const int tid = threadIdx.x, wave = tid >> 6, lane = tid & 63;
  const int quad = lane >> 4, lcol = lane & 15;
  const int win = blockIdx.x, h = wave;
  const size_t hb = (((size_t)win * 4 + h) * NTOK) * 32;
  const unsigned short* vbase = vgt + (((size_t)win * 4 + h) * 32) * 112;

  unsigned short* plh = smem + h * (16 * 132);   // wave-private P tile [16][132]

  // zero plh cols 112..127 (A-frag K-range pads; cols 98..111 get exp->0 writes)
  for (int idx = lane; idx < 16 * 16; idx += 64) {
    int rr = idx >> 4, c = 112 + (idx & 15);
    plh[rr * 132 + c] = 0;
  }

  // ---- Q/K fragments direct from global (rows clamped at 97; pad rows discarded) ----
  bf16x8 aq[7], bk[7];
#pragma unroll
  for (int t = 0; t < 7; ++t) {
    int row = min(t * 16 + lcol, NTOK - 1);
    aq[t] = *(const bf16x8*)(qg + hb + (size_t)row * 32 + quad * 8);
    bk[t] = *(const bf16x8*)(kg + hb + (size_t)row * 32 + quad * 8);
  }

  const float* bh = bias + h * BIAS_N;
  f32x4 o[7][2];
  for (int mt = 0; mt < 7; ++mt) {
    // scores S[i][j], i = mt*16+quad*4+r, j = nt*16+lcol
    f32x4 s[7];
#pragma unroll
    for (int nt = 0; nt < 7; ++nt)
      s[nt] = __builtin_amdgcn_mfma_f32_16x16x32_bf16(aq[mt], bk[nt],
                                                      (f32x4){0.f, 0.f, 0.f, 0.f}, 0, 0, 0);
    const int ib = mt * 16 + quad * 4;
#pragma unroll
    for (int nt = 0; nt < 7; ++nt) {
      int j = nt * 16 + lcol;
      bool jv = j < NTOK;
#pragma unroll
      for (int r = 0; r < 4; ++r) {
        int ic = min(ib + r, NTOK - 1);
        s[nt][r] = jv ? (s[nt][r] + bh[ic * NTOK + j]) : -3.0e38f;
      }
    }
    // row softmax: local over nt, then shfl_xor across the 16-lane column group
    float mx[4], sum[4], inv[4];
#pragma unroll
    for (int r = 0; r < 4; ++r) {
      float m = s[0][r];
#pragma unroll
      for (int nt = 1; nt < 7; ++nt) m = fmaxf(m, s[nt][r]);
      mx[r] = m;
    }
#pragma unroll
    for (int off = 1; off < 16; off <<= 1)
#pragma unroll
      for (int r = 0; r < 4; ++r) mx[r] = fmaxf(mx[r], __shfl_xor(mx[r], off));
#pragma unroll
    for (int r = 0; r < 4; ++r) sum[r] = 0.f;
#pragma unroll
    for (int nt = 0; nt < 7; ++nt)
#pragma unroll
      for (int r = 0; r < 4; ++r) {
        float e = __expf(s[nt][r] - mx[r]);
        s[nt][r] = e; sum[r] += e;
      }
#pragma unroll
    for (int off = 1; off < 16; off <<= 1)
#pragma unroll
      for (int r = 0; r < 4; ++r) sum[r] += __shfl_xor(sum[r], off);
#pragma unroll
    for (int r = 0; r < 4; ++r) inv[r] = 1.0f / sum[r];
    // write P (bf16) to own LDS tile in A-layout source form [i][j] (wave-private)
#pragma unroll
    for (int nt = 0; nt < 7; ++nt)
#pragma unroll
      for (int r = 0; r < 4; ++r)
        plh[(quad * 4 + r) * 132 + nt * 16 + lcol] = f2b(s[nt][r] * inv[r]);
    // PV: A = P tile (K=128 padded with zeros), B = V^T frags direct from global
#pragma unroll
    for (int n2 = 0; n2 < 2; ++n2) {
      f32x4 acc = (f32x4){0.f, 0.f, 0.f, 0.f};
#pragma unroll
      for (int kp = 0; kp < 4; ++kp) {
        bf16x8 a = *(const bf16x8*)(plh + lcol * 132 + kp * 32 + quad * 8);
        bf16x8 b = *(const bf16x8*)(vbase + (size_t)(n2 * 16 + lcol) * 112 +
                                    kp * 32 + quad * 8);
        acc = __builtin_amdgcn_mfma_f32_16x16x32_bf16(a, b, acc, 0, 0, 0);
      }
      o[mt][n2] = acc;
    }
  }
  __syncthreads();   // all waves' plh use done before olds overlays smem

  // ---- attn-out -> LDS [112][136], full 128 channels ----
  unsigned short* olds = smem;
#pragma unroll
  for (int mt = 0; mt < 7; ++mt)
#pragma unroll
    for (int n2 = 0; n2 < 2; ++n2)
#pragma unroll
      for (int r = 0; r < 4; ++r)
        olds[(mt * 16 + quad * 4 + r) * 136 + h * 32 + n2 * 16 + lcol] = f2b(o[mt][n2][r]);
  __syncthreads();

  // ---- proj into registers ----
  f32x4 pr[2][7];
  for (int t2 = 0; t2 < 2; ++t2) {
    const int n = (h * 2 + t2) * 16 + lcol;
    bf16x8 bw[4];
#pragma unroll
    for (int kp = 0; kp < 4; ++kp)
      bw[kp] = *(const bf16x8*)(wp_t + (size_t)n * 128 + kp * 32 + quad * 8);
    for (int mt = 0; mt < 7; ++mt) {
      f32x4 acc = (f32x4){0.f, 0.f, 0.f, 0.f};
#pragma unroll
      for (int kp = 0; kp < 4; ++kp) {
        bf16x8 a = *(const bf16x8*)(olds + (mt * 16 + lcol) * 136 + kp * 32 + quad * 8);
        acc = __builtin_amdgcn_mfma_f32_16x16x32_bf16(a, bw[kp], acc, 0, 0, 0);
      }
      pr[t2][mt] = acc;
    }
  }
  __syncthreads();   // all olds reads done before pout overlays smem

  // ---- two-pass epilogue: pout[56][132] f32, coalesced residual + store ----
  const int bb = win >> 8, rW = win & 255;
  const int wd = rW >> 6, r2 = rW & 63, wh = r2 >> 3, ww = r2 & 7;
  float* pout = (float*)smem;
  for (int pass = 0; pass < 2; ++pass) {
    const int mlo = pass * 56;
    for (int t2 = 0; t2 < 2; ++t2) {
      const int n = (h * 2 + t2) * 16 + lcol;
      const float bc = par[P_PROJB + n];
#pragma unroll
      for (int mt = 0; mt < 7; ++mt)
#pragma unroll
        for (int r = 0; r < 4; ++r) {
          int m = mt * 16 + quad * 4 + r;
          if (m >= mlo && m < mlo + 56 && m < NTOK)
            pout[(m - mlo) * 132 + n] = pr[t2][mt][r] + bc;
        }
    }
    __syncthreads();
    const int c = (tid & 31) * 4;
    for (int i = tid >> 5; i < 56; i += 8) {
      int m = mlo + i;
      if (m >= NTOK) break;
      int td = m / 49, r3 = m % 49, th = r3 / 7, tw = r3 % 7;
      int sd = (wd * 2 + td + 1) & 7;
      int sh = (wh * 7 + th + 3) % 56;
      int sw = (ww * 7 + tw + 3) % 56;
      size_t base = ((((size_t)bb * 8 + sd) * 56 + sh) * 56 + sw) * 128 + c;
      float4 p = *(const float4*)(pout + i * 132 + c);
      if (f32) {
        const float4 xr = *(const float4*)((const float*)x + base);
        float4 ov = make_float4(p.x + xr.x, p.y + xr.y, p.z + xr.z, p.w + xr.w);
        *(float4*)((float*)out + base) = ov;
      } else {
        const ushort4 xr = *(const ushort4*)((const unsigned short*)x + base);
        ushort4 ov;
        ov.x = f2b(p.x + b2f(xr.x)); ov.y = f2b(p.y + b2f(xr.y));
        ov.z = f2b(p.z + b2f(xr.z)); ov.w = f2b(p.w + b2f(xr.w));
        *(ushort4*)((unsigned short*)out + base) = ov;
      }
    }
    if (pass == 0) __syncthreads();   // pout reused by pass 1
  }
}

// ---------------- K5: LN2 + MLP1(gelu) + MLP2 + residual (unchanged from r3) ----------------
__global__ __launch_bounds__(256) void mlp_kernel(
    const unsigned short* __restrict__ w1_t, const unsigned short* __restrict__ w2_t,
    const float* __restrict__ par, const int* __restrict__ flag,
    void* __restrict__ out) {
  __shared__ __align__(16) unsigned short lnt[32 * 136];   //  8704 B
  __shared__ __align__(16) unsigned short hbuf[32 * 264];  // 16896 B; pout overlays
  const int f32 = *flag;
  const int tid = threadIdx.x, wave = tid >> 6, lane = tid & 63;
  const int quad = lane >> 4, lcol = lane & 15;
  const int m0 = blockIdx.x * 32;

  for (int t = wave; t < 32; t += 4) {
    int c0 = lane * 2;
    float2 f = ldf2(out, (size_t)(m0 + t) * 128 + c0, f32);
    float s = f.x + f.y, ss = f.x * f.x + f.y * f.y;
#pragma unroll
    for (int off = 32; off >= 1; off >>= 1) { s += __shfl_xor(s, off); ss += __shfl_xor(ss, off); }
    float mu = s * (1.0f / 128.0f);
    float var = ss * (1.0f / 128.0f) - mu * mu;
    float rs = rsqrtf(var + 1e-5f);
    float y0 = (f.x - mu) * rs * par[P_LN2G + c0] + par[P_LN2B + c0];
    float y1 = (f.y - mu) * rs * par[P_LN2G + c0 + 1] + par[P_LN2B + c0 + 1];
    *(uint32_t*)(lnt + t * 136 + c0) = (uint32_t)f2b(y0) | ((uint32_t)f2b(y1) << 16);
  }
  __syncthreads();

  f32x4 acc2[2][2];
#pragma unroll
  for (int a = 0; a < 2; ++a)
#pragma unroll
    for (int b = 0; b < 2; ++b) acc2[a][b] = (f32x4){0.f, 0.f, 0.f, 0.f};

  for (int g = 0; g < 2; ++g) {
    for (int p = 0; p < 4; ++p) {
      const int nl = p * 64 + wave * 16 + lcol;
      const int n = g * 256 + nl;
      bf16x8 bfr[4];
#pragma unroll
      for (int ks = 0; ks < 4; ++ks)
        bfr[ks] = *(const bf16x8*)(w1_t + (size_t)n * 128 + ks * 32 + quad * 8);
      const float bc = par[P_B1 + n];
#pragma unroll
      for (int mt = 0; mt < 2; ++mt) {
        f32x4 acc = (f32x4){0.f, 0.f, 0.f, 0.f};
#pragma unroll
        for (int ks = 0; ks < 4; ++ks) {
          bf16x8 a = *(const bf16x8*)(lnt + (mt * 16 + lcol) * 136 + ks * 32 + quad * 8);
          acc = __builtin_amdgcn_mfma_f32_16x16x32_bf16(a, bfr[ks], acc, 0, 0, 0);
        }
#pragma unroll
        for (int rr = 0; rr < 4; ++rr) {
          int m = mt * 16 + quad * 4 + rr;
          float v = acc[rr] + bc;
          v = 0.5f * v * (1.0f + erff(v * 0.70710678118654752f));
          hbuf[m * 264 + nl] = f2b(v);
        }
      }
    }
    __syncthreads();

#pragma unroll
    for (int np = 0; np < 2; ++np) {
      const int n = np * 64 + wave * 16 + lcol;
      for (int kp = 0; kp < 2; ++kp) {
        bf16x8 bfr[4];
#pragma unroll
        for (int ks = 0; ks < 4; ++ks)
          bfr[ks] = *(const bf16x8*)(w2_t + (size_t)n * 512 + g * 256 + kp * 128 +
                                     ks * 32 + quad * 8);
#pragma unroll
        for (int mt = 0; mt < 2; ++mt) {
#pragma unroll
          for (int ks = 0; ks < 4; ++ks) {
            bf16x8 a = *(const bf16x8*)(hbuf + (mt * 16 + lcol) * 264 + kp * 128 +
                                        ks * 32 + quad * 8);
            acc2[np][mt] = __builtin_amdgcn_mfma_f32_16x16x32_bf16(a, bfr[ks], acc2[np][mt], 0, 0, 0);
          }
        }
      }
    }
    __syncthreads();
  }

  float* pout = (float*)hbuf;
#pragma unroll
  for (int np = 0; np < 2; ++np) {
    const int n = np * 64 + wave * 16 + lcol;
    const float bc = par[P_B2 + n];
#pragma unroll
    for (int mt = 0; mt < 2; ++mt)
#pragma unroll
      for (int rr = 0; rr < 4; ++rr)
        pout[(mt * 16 + quad * 4 + rr) * 132 + n] = acc2[np][mt][rr] + bc;
  }
  __syncthreads();

  for (int i = tid; i < 1024; i += 256) {
    int t = i >> 5, c = (i & 31) * 4;
    size_t base = (size_t)(m0 + t) * 128 + c;
    float4 p = *(const float4*)(pout + t * 132 + c);
    if (f32) {
      const float4 xr = *(const float4*)((const float*)out + base);
      float4 ov = make_float4(p.x + xr.x, p.y + xr.y, p.z + xr.z, p.w + xr.w);
      *(float4*)((float*)out + base) = ov;
    } else {
      const ushort4 xr = *(const ushort4*)((const unsigned short*)out + base);
      ushort4 ov;
      ov.x = f2b(p.x + b2f(xr.x)); ov.y = f2b(p.y + b2f(xr.y));
      ov.z = f2b(p.z + b2f(xr.z)); ov.w = f2b(p.w + b2f(xr.w));
      *(ushort4*)((unsigned short*)out + base) = ov;
    }
  }
}

// ---------------- host launch ----------------
extern "C" void kernel_launch(void* const* d_in, const int* in_sizes, int n_in,
                              void* d_out, int out_size, void* d_ws, size_t ws_size,
                              hipStream_t stream) {
  const void* x      = d_in[0];
  const int*  rel    = (const int*)d_in[1];
  const void* rpb    = d_in[2];
  const void* qkv_w  = d_in[3];
  const void* qkv_b  = d_in[4];
  const void* proj_w = d_in[5];
  const void* proj_b = d_in[6];
  const void* ln1_g  = d_in[7];
  const void* ln1_b  = d_in[8];
  const void* ln2_g  = d_in[9];
  const void* ln2_b  = d_in[10];
  const void* w1     = d_in[11];
  const void* b1     = d_in[12];
  const void* w2     = d_in[13];
  const void* b2     = d_in[14];

  char* ws = (char*)d_ws;
  unsigned short* qg   = (unsigned short*)(ws + QG_OFF);
  unsigned short* kg   = (unsigned short*)(ws + KG_OFF);
  unsigned short* vgt  = (unsigned short*)(ws + VGT_OFF);
  unsigned short* zpad = (unsigned short*)(ws + ZPAD_OFF);
  float*          bias = (float*)(ws + BIAS_OFF);
  unsigned short* wq_t = (unsigned short*)(ws + WQ_OFF);
  unsigned short* wp_t = (unsigned short*)(ws + WP_OFF);
  unsigned short* w1_t = (unsigned short*)(ws + W1_OFF);
  unsigned short* w2_t = (unsigned short*)(ws + W2_OFF);
  float*          par  = (float*)(ws + PAR_OFF);
  int*            flag = (int*)(ws + FLAG_OFF);

  detect_kernel<<<1, 256, 0, stream>>>((const uint32_t*)x, flag);
  prep_kernel<<<791, 256, 0, stream>>>(qkv_w, proj_w, w1, w2, ln1_g, ln1_b, ln2_g,
                                       ln2_b, qkv_b, proj_b, b1, b2, flag,
                                       wq_t, wp_t, w1_t, w2_t, par, zpad);
  bias_kernel<<<(4 * BIAS_N + 255) / 256, 256, 0, stream>>>(rel, rpb, flag, bias);
  qkv_win_kernel<<<NWIN, 256, 0, stream>>>(x, flag, wq_t, par, qg, kg, vgt);
  attn_fused_kernel<<<NWIN, 256, 0, stream>>>(qg, kg, vgt, bias, wp_t, par, x, flag, d_out);
  mlp_kernel<<<100352 / 32, 256, 0, stream>>>(w1_t, w2_t, par, flag, d_out);
}